// Round 1
// baseline (1930.221 us; speedup 1.0000x reference)
//
#include <hip/hip_runtime.h>
#include <math.h>
#include <cstdint>

#define N_NODES 20000
#define N_EDGES 60000
#define N_GRAPHS 512
#define NT 4

// ---------------- CSR build ----------------
__global__ void count_deg_k(const int* __restrict__ dst, int* __restrict__ deg) {
  int e = blockIdx.x * blockDim.x + threadIdx.x;
  if (e < N_EDGES) atomicAdd(&deg[dst[e]], 1);
}

__global__ void scan_rowptr_k(const int* __restrict__ deg, int* __restrict__ rp) {
  __shared__ int ss[1024];
  int tid = threadIdx.x;
  const int per = (N_NODES + 1023) / 1024;  // 20
  int base = tid * per;
  int s = 0;
  for (int i = 0; i < per; i++) { int idx = base + i; if (idx < N_NODES) s += deg[idx]; }
  ss[tid] = s;
  __syncthreads();
  for (int off = 1; off < 1024; off <<= 1) {
    int v = (tid >= off) ? ss[tid - off] : 0;
    __syncthreads();
    ss[tid] += v;
    __syncthreads();
  }
  int run = ss[tid] - s;  // exclusive prefix
  for (int i = 0; i < per; i++) {
    int idx = base + i;
    if (idx < N_NODES) { rp[idx] = run; run += deg[idx]; }
  }
  if (tid == 0) rp[N_NODES] = ss[1023];
}

__global__ void fill_csr_k(const int* __restrict__ dst, const int* __restrict__ rp,
                           int* __restrict__ cur, int* __restrict__ eids) {
  int e = blockIdx.x * blockDim.x + threadIdx.x;
  if (e < N_EDGES) {
    int d = dst[e];
    int pos = atomicAdd(&cur[d], 1);
    eids[rp[d] + pos] = e;
  }
}

__global__ void amp_k(const int* __restrict__ deg, float* __restrict__ amp, float adl) {
  int n = blockIdx.x * blockDim.x + threadIdx.x;
  if (n < N_NODES) {
    float d = (float)(deg[n] > 0 ? deg[n] : 1);
    amp[n] = logf(d + 1.0f) / adl;
  }
}

// ---------------- generic tiled SGEMM (64x64, 256 threads, 4x4/thread) ----------------
// MODE 0: plain A [M,K] row-major (lda). MODE 1: A is the virtual edge-feature
// matrix h[e,k] = [x[dst[e]] | x[src[e]] | edge_attr[e] @ EW + EB], K = 3F.
template <int MODE>
__global__ __launch_bounds__(256) void gemm64_k(
    const float* __restrict__ A, const float* __restrict__ B, float* __restrict__ C,
    const float* __restrict__ bias, int M, int N, int K, int lda, int ldb, int ldc,
    long long bsA, long long bsB, long long bsC,
    const float* __restrict__ X, int F,
    const int* __restrict__ srcI, const int* __restrict__ dstI,
    const float* __restrict__ EA, const float* __restrict__ EW, const float* __restrict__ EB) {
  __shared__ float As[16][65];
  __shared__ float Bs[16][64];
  __shared__ int sdst[64], ssrc[64];
  __shared__ float sea[64][3];

  const int tx = threadIdx.x, ty = threadIdx.y;
  const int tid = ty * 16 + tx;
  const int m0 = blockIdx.x * 64, n0 = blockIdx.y * 64;
  const int z = blockIdx.z;
  const float* Ab = A + bsA * z;
  const float* Bb = B + bsB * z;
  float* Cb = C + bsC * z;

  if (MODE == 1) {
    if (tid < 64) {
      int e = m0 + tid;
      int ee = (e < M) ? e : (M - 1);
      sdst[tid] = dstI[ee];
      ssrc[tid] = srcI[ee];
      sea[tid][0] = EA[ee * 3 + 0];
      sea[tid][1] = EA[ee * 3 + 1];
      sea[tid][2] = EA[ee * 3 + 2];
    }
    __syncthreads();
  }

  float acc[4][4] = {};
  for (int k0 = 0; k0 < K; k0 += 16) {
#pragma unroll
    for (int it = 0; it < 4; ++it) {  // A tile: 64m x 16k
      int idx = it * 256 + tid;
      int m = idx >> 4, kk = idx & 15;
      int gm = m0 + m, gk = k0 + kk;
      float v = 0.f;
      if (gm < M && gk < K) {
        if (MODE == 0) {
          v = Ab[(long long)gm * lda + gk];
        } else {
          if (gk < F) v = X[(long long)sdst[m] * F + gk];
          else if (gk < 2 * F) v = X[(long long)ssrc[m] * F + (gk - F)];
          else {
            int k2 = gk - 2 * F;
            v = EB[k2] + sea[m][0] * EW[k2] + sea[m][1] * EW[F + k2] + sea[m][2] * EW[2 * F + k2];
          }
        }
      }
      As[kk][m] = v;
    }
#pragma unroll
    for (int it = 0; it < 4; ++it) {  // B tile: 16k x 64n
      int kk = it * 4 + (tid >> 6);
      int n = tid & 63;
      int gk = k0 + kk, gn = n0 + n;
      Bs[kk][n] = (gk < K && gn < N) ? Bb[(long long)gk * ldb + gn] : 0.f;
    }
    __syncthreads();
#pragma unroll
    for (int kk = 0; kk < 16; ++kk) {
      float a[4], b[4];
#pragma unroll
      for (int i = 0; i < 4; i++) a[i] = As[kk][ty * 4 + i];
#pragma unroll
      for (int j = 0; j < 4; j++) b[j] = Bs[kk][tx * 4 + j];
#pragma unroll
      for (int i = 0; i < 4; i++)
#pragma unroll
        for (int j = 0; j < 4; j++) acc[i][j] += a[i] * b[j];
    }
    __syncthreads();
  }
#pragma unroll
  for (int i = 0; i < 4; i++) {
    int gm = m0 + ty * 4 + i;
    if (gm >= M) continue;
#pragma unroll
    for (int j = 0; j < 4; j++) {
      int gn = n0 + tx * 4 + j;
      if (gn < N) {
        float v = acc[i][j];
        if (bias) v += bias[gn];
        Cb[(long long)gm * ldc + gn] = v;
      }
    }
  }
}

// ---------------- PNA aggregation (mean/min/max/std per node) ----------------
__global__ void aggregate_k(const float* __restrict__ msg, const int* __restrict__ rp,
                            const int* __restrict__ eids, float* __restrict__ agg, int F) {
  const int C = NT * F;
  long long idx = (long long)blockIdx.x * blockDim.x + threadIdx.x;
  long long total = (long long)N_NODES * C;
  if (idx >= total) return;
  int n = (int)(idx / C);
  int c = (int)(idx % C);
  int t = c / F, f = c % F;
  int s = rp[n], e = rp[n + 1];
  int deg = e - s;
  float sum = 0.f, sq = 0.f, mn = INFINITY, mx = -INFINITY;
  for (int i = s; i < e; i++) {
    int eid = eids[i];
    float v = msg[(long long)eid * C + c];
    sum += v; sq += v * v;
    mn = fminf(mn, v); mx = fmaxf(mx, v);
  }
  float degc = (float)(deg > 0 ? deg : 1);
  float mean = sum / degc;
  float var = sq / degc - mean * mean;
  if (var < 0.f) var = 0.f;
  float stdv = sqrtf(var + 1e-5f);
  if (deg == 0) { mn = 0.f; mx = 0.f; }
  long long base = (long long)n * (4 * C) + (long long)t * (4 * F);
  agg[base + f] = mean;
  agg[base + F + f] = mn;
  agg[base + 2 * F + f] = mx;
  agg[base + 3 * F + f] = stdv;
}

// ---------------- weight repacks for one layer ----------------
// Bmsg[f][t*F+o] = prw[t][f][o]          (3F x 4F)
// Wcat[t][j][col] col<18: pow[t][F+j][col]; col<36: pow[t][5F+j][col-18]; else pow[t][9F+j][col-36]
// W0cat[f][t*18+o] = pow[t][f][o]        (F x 72)
__global__ void repack_k(const float* __restrict__ prw, const float* __restrict__ pw,
                         float* __restrict__ Bmsg, float* __restrict__ Wcat,
                         float* __restrict__ W0cat, int F) {
  int F3 = 3 * F, F4 = 4 * F;
  int nB = F3 * F4, nW = NT * F4 * 54, n0 = F * 72;
  int idx = blockIdx.x * blockDim.x + threadIdx.x;
  if (idx < nB) {
    int f = idx / F4, c = idx % F4;
    int t = c / F, o = c % F;
    Bmsg[idx] = prw[((long long)t * F3 + f) * F + o];
  } else if (idx < nB + nW) {
    int j2 = idx - nB;
    int t = j2 / (F4 * 54);
    int rem = j2 % (F4 * 54);
    int j = rem / 54, col = rem % 54;
    int seg = col / 18, o = col % 18;
    int row = (seg == 0) ? (F + j) : ((seg == 1) ? (5 * F + j) : (9 * F + j));
    Wcat[j2] = pw[((long long)t * (13 * F) + row) * 18 + o];
  } else if (idx < nB + nW + n0) {
    int j2 = idx - nB - nW;
    int f = j2 / 72, c = j2 % 72;
    int t = c / 18, o = c % 18;
    W0cat[j2] = pw[((long long)t * (13 * F) + f) * 18 + o];
  }
}

// y0[n][t*18+o] += P[n][t*54+o] + amp*P[n][t*54+18+o] + P[n][t*54+36+o]/amp
__global__ void combine_k(float* __restrict__ y0, const float* __restrict__ P,
                          const float* __restrict__ amp) {
  int idx = blockIdx.x * blockDim.x + threadIdx.x;
  if (idx >= N_NODES * 72) return;
  int n = idx / 72, c = idx % 72;
  int t = c / 18, o = c % 18;
  float a = amp[n];
  const float* p = P + (long long)n * 216 + t * 54;
  y0[idx] += p[o] + a * p[18 + o] + p[36 + o] / a;
}

// ---------------- BatchNorm over nodes ----------------
__global__ void bnstats_k(const float* __restrict__ y, double* __restrict__ sums) {
  int c = threadIdx.x % 72;
  int q = threadIdx.x / 72;  // 0..3
  __shared__ float ps[288], pq[288];
  int rows_per_block = (N_NODES + gridDim.x - 1) / gridDim.x;
  int r0 = blockIdx.x * rows_per_block;
  int r1 = r0 + rows_per_block;
  if (r1 > N_NODES) r1 = N_NODES;
  float s = 0.f, sq = 0.f;
  for (int r = r0 + q; r < r1; r += 4) {
    float v = y[(long long)r * 72 + c];
    s += v; sq += v * v;
  }
  ps[threadIdx.x] = s; pq[threadIdx.x] = sq;
  __syncthreads();
  if (q == 0) {
    s = ps[c] + ps[72 + c] + ps[144 + c] + ps[216 + c];
    sq = pq[c] + pq[72 + c] + pq[144 + c] + pq[216 + c];
    atomicAdd(&sums[c], (double)s);
    atomicAdd(&sums[72 + c], (double)sq);
  }
}

__global__ void bnrelu_k(const float* __restrict__ y, const double* __restrict__ sums,
                         const float* __restrict__ g, const float* __restrict__ be,
                         float* __restrict__ out) {
  int idx = blockIdx.x * blockDim.x + threadIdx.x;
  if (idx >= N_NODES * 72) return;
  int c = idx % 72;
  double mud = sums[c] / (double)N_NODES;
  double vard = sums[72 + c] / (double)N_NODES - mud * mud;
  if (vard < 0.0) vard = 0.0;
  float scale = g[c] / sqrtf((float)vard + 1e-5f);
  float shift = be[c] - (float)mud * scale;
  float v = y[idx] * scale + shift;
  out[idx] = v > 0.f ? v : 0.f;
}

// ---------------- pooling ----------------
__global__ void pool_k(const float* __restrict__ h, const int* __restrict__ batch,
                       float* __restrict__ gp) {
  int idx = blockIdx.x * blockDim.x + threadIdx.x;
  if (idx >= N_NODES * 72) return;
  int n = idx / 72, c = idx % 72;
  atomicAdd(&gp[(long long)batch[n] * 72 + c], h[idx]);
}

// ---------------- MLP heads (one block per head) ----------------
struct HeadP {
  const float *w1, *b1, *g1, *be1, *w2, *b2, *g2, *be2, *w3, *b3;
};

__device__ inline float wred(float v) {
#pragma unroll
  for (int off = 32; off > 0; off >>= 1) v += __shfl_xor(v, off);
  return v;
}

__global__ __launch_bounds__(512) void heads_k(const float* __restrict__ gp, HeadP hA,
                                               HeadP hB, HeadP hC, float* __restrict__ out) {
  HeadP hp = (blockIdx.x == 0) ? hA : ((blockIdx.x == 1) ? hB : hC);
  const int r = threadIdx.x;          // one graph-row per thread
  const int wave = r >> 6, lane = r & 63;
  __shared__ float wsum[50 * 8], wsq[50 * 8], scale_s[50], shift_s[50];

  // GEMM1: [512,72]x[72,50]
  float acc[50];
#pragma unroll
  for (int o = 0; o < 50; o++) acc[o] = hp.b1[o];
  for (int k = 0; k < 72; k++) {
    float gv = gp[r * 72 + k];
    const float* w = hp.w1 + k * 50;
#pragma unroll
    for (int o = 0; o < 50; o++) acc[o] += gv * w[o];
  }
  // BN1 stats (shuffle + LDS partials)
#pragma unroll
  for (int o = 0; o < 50; o++) {
    float s = wred(acc[o]);
    float q = wred(acc[o] * acc[o]);
    if (lane == 0) { wsum[o * 8 + wave] = s; wsq[o * 8 + wave] = q; }
  }
  __syncthreads();
  if (r < 50) {
    float s = 0.f, q = 0.f;
#pragma unroll
    for (int i = 0; i < 8; i++) { s += wsum[r * 8 + i]; q += wsq[r * 8 + i]; }
    float mu = s / (float)N_GRAPHS;
    float var = q / (float)N_GRAPHS - mu * mu;
    if (var < 0.f) var = 0.f;
    float sc = hp.g1[r] / sqrtf(var + 1e-5f);
    scale_s[r] = sc;
    shift_s[r] = hp.be1[r] - mu * sc;
  }
  __syncthreads();
  float h1[50];
#pragma unroll
  for (int o = 0; o < 50; o++) {
    float v = acc[o] * scale_s[o] + shift_s[o];
    h1[o] = v > 0.f ? v : 0.f;
  }
  // GEMM2: [512,50]x[50,25]
  float acc2[25];
#pragma unroll
  for (int o = 0; o < 25; o++) acc2[o] = hp.b2[o];
#pragma unroll
  for (int k = 0; k < 50; k++) {
    const float* w = hp.w2 + k * 25;
#pragma unroll
    for (int o = 0; o < 25; o++) acc2[o] += h1[k] * w[o];
  }
#pragma unroll
  for (int o = 0; o < 25; o++) {
    float s = wred(acc2[o]);
    float q = wred(acc2[o] * acc2[o]);
    if (lane == 0) { wsum[o * 8 + wave] = s; wsq[o * 8 + wave] = q; }
  }
  __syncthreads();
  if (r < 25) {
    float s = 0.f, q = 0.f;
#pragma unroll
    for (int i = 0; i < 8; i++) { s += wsum[r * 8 + i]; q += wsq[r * 8 + i]; }
    float mu = s / (float)N_GRAPHS;
    float var = q / (float)N_GRAPHS - mu * mu;
    if (var < 0.f) var = 0.f;
    float sc = hp.g2[r] / sqrtf(var + 1e-5f);
    scale_s[r] = sc;
    shift_s[r] = hp.be2[r] - mu * sc;
  }
  __syncthreads();
  float h2[25];
#pragma unroll
  for (int o = 0; o < 25; o++) {
    float v = acc2[o] * scale_s[o] + shift_s[o];
    h2[o] = v > 0.f ? v : 0.f;
  }
  // GEMM3: [512,25]x[25,od]
  int od = (blockIdx.x == 0) ? 3 : 7;
  float acc3[7];
#pragma unroll
  for (int o = 0; o < 7; o++) acc3[o] = (o < od) ? hp.b3[o] : 0.f;
#pragma unroll
  for (int k = 0; k < 25; k++) {
    const float* w = hp.w3 + k * od;
#pragma unroll
    for (int o = 0; o < 7; o++)
      if (o < od) acc3[o] += h2[k] * w[o];
  }
  float* og = out + r * 20;  // [512][2][10]
  if (blockIdx.x == 0) {
#pragma unroll
    for (int j = 0; j < 3; j++) {
      float v = tanhf(acc3[j]);
      og[7 + j] = v;
      og[17 + j] = v;
    }
  } else {
    const float unit[7] = {1.f, 1.f, 100.f, 0.01f, 1000.f, 0.f, 1e-5f};
    int base = (blockIdx.x == 1) ? 0 : 10;
#pragma unroll
    for (int j = 0; j < 7; j++) {
      float v = acc3[j];
      v = v > 0.f ? v : 0.f;
      og[base + j] = v + unit[j];
    }
  }
}

// ---------------- host launch ----------------
static inline char* alignp(char* p, size_t a) {
  return (char*)(((uintptr_t)p + (a - 1)) & ~(uintptr_t)(a - 1));
}

extern "C" void kernel_launch(void* const* d_in, const int* in_sizes, int n_in, void* d_out,
                              int out_size, void* d_ws, size_t ws_size, hipStream_t stream) {
  const float* x = (const float*)d_in[0];
  const float* edge_attr = (const float*)d_in[1];
  const int* srcp = (const int*)d_in[2];
  const int* dstp = srcp + N_EDGES;
  const int* batch = (const int*)d_in[3];

  const float* EWv[4], *EBv[4], *PRW[4], *PRB[4], *PW[4], *POB[4], *LWv[4], *LBv[4], *Gv[4], *BEv[4];
  EWv[0] = (const float*)d_in[4];  EBv[0] = (const float*)d_in[5];
  PRW[0] = (const float*)d_in[6];  PRB[0] = (const float*)d_in[7];
  PW[0] = (const float*)d_in[8];   POB[0] = (const float*)d_in[9];
  LWv[0] = (const float*)d_in[10]; LBv[0] = (const float*)d_in[11];
  Gv[0] = (const float*)d_in[12];  BEv[0] = (const float*)d_in[13];
  const float* cs_ew = (const float*)d_in[14];
  const float* cs_eb = (const float*)d_in[15];
  const float* cs_prw = (const float*)d_in[16];
  const float* cs_prb = (const float*)d_in[17];
  const float* cs_pow = (const float*)d_in[18];
  const float* cs_pob = (const float*)d_in[19];
  const float* cs_lw = (const float*)d_in[20];
  const float* cs_lb = (const float*)d_in[21];
  const float* cs_g = (const float*)d_in[22];
  const float* cs_be = (const float*)d_in[23];
  for (int i = 1; i < 4; i++) {
    int j = i - 1;
    EWv[i] = cs_ew + j * 3 * 72;        EBv[i] = cs_eb + j * 72;
    PRW[i] = cs_prw + j * 4 * 216 * 72; PRB[i] = cs_prb + j * 4 * 72;
    PW[i] = cs_pow + j * 4 * 936 * 18;  POB[i] = cs_pob + j * 4 * 18;
    LWv[i] = cs_lw + j * 72 * 72;       LBv[i] = cs_lb + j * 72;
    Gv[i] = cs_g + j * 72;              BEv[i] = cs_be + j * 72;
  }
  HeadP heads[3];
  for (int m = 0; m < 3; m++) {
    const float** pp = (const float**)&heads[m];
    for (int k = 0; k < 10; k++) pp[k] = (const float*)d_in[24 + m * 10 + k];
  }

  // workspace carve
  char* p = (char*)d_ws;
  int* deg_i = (int*)p;      p += N_NODES * 4;
  int* cursor = (int*)p;     p += N_NODES * 4;
  int* row_ptr = (int*)p;    p += (N_NODES + 1) * 4;
  int* eids = (int*)p;       p += N_EDGES * 4;
  p = alignp(p, 256);
  float* amp = (float*)p;    p += N_NODES * 4;
  p = alignp(p, 256);
  float* msg = (float*)p;    p += (size_t)N_EDGES * 288 * 4;  // also aliased as P-buffer
  float* Pbuf = msg;                                          // msg dead when P is live
  p = alignp(p, 256);
  float* agg = (float*)p;    p += (size_t)N_NODES * 1152 * 4;
  p = alignp(p, 256);
  float* Bmsg = (float*)p;   p += 216 * 288 * 4;
  float* Wcat = (float*)p;   p += 4 * 288 * 54 * 4;
  float* W0cat = (float*)p;  p += 72 * 72 * 4;
  p = alignp(p, 256);
  float* y0 = (float*)p;     p += (size_t)N_NODES * 72 * 4;
  float* y1 = (float*)p;     p += (size_t)N_NODES * 72 * 4;
  float* xA = (float*)p;     p += (size_t)N_NODES * 72 * 4;
  float* xB = (float*)p;     p += (size_t)N_NODES * 72 * 4;
  p = alignp(p, 256);
  double* bnsums = (double*)p; p += 144 * 8;
  float* gpool = (float*)p;  p += (size_t)N_GRAPHS * 72 * 4;
  (void)ws_size; (void)n_in; (void)in_sizes; (void)out_size;

  // AVG_DEG_LOG on host
  static const double hist[7] = {67167, 3157428, 5106064, 885236, 453935, 0, 11152};
  double num = 0, den = 0;
  for (int i = 0; i < 7; i++) { num += log((double)(i + 1)) * hist[i]; den += hist[i]; }
  float adl = (float)(num / den);

  dim3 blk16(16, 16);

  // CSR + amp (edge structure constant across layers)
  hipMemsetAsync(deg_i, 0, 2 * N_NODES * 4, stream);  // deg_i + cursor (adjacent)
  hipMemsetAsync(gpool, 0, N_GRAPHS * 72 * 4, stream);
  count_deg_k<<<(N_EDGES + 255) / 256, 256, 0, stream>>>(dstp, deg_i);
  scan_rowptr_k<<<1, 1024, 0, stream>>>(deg_i, row_ptr);
  fill_csr_k<<<(N_EDGES + 255) / 256, 256, 0, stream>>>(dstp, row_ptr, cursor, eids);
  amp_k<<<(N_NODES + 255) / 256, 256, 0, stream>>>(deg_i, amp, adl);

  const float* xin = x;
  for (int l = 0; l < 4; l++) {
    int F = (l == 0) ? 9 : 72;
    int F3 = 3 * F, F4 = 4 * F, C = NT * F;
    float* xout = (l & 1) ? xB : xA;

    // weight repacks
    int nrep = F3 * F4 + NT * F4 * 54 + F * 72;
    repack_k<<<(nrep + 255) / 256, 256, 0, stream>>>(PRW[l], PW[l], Bmsg, Wcat, W0cat, F);

    // msg = h @ Bmsg + prb   (h gathered on the fly)
    dim3 gm((N_EDGES + 63) / 64, (C + 63) / 64, 1);
    gemm64_k<1><<<gm, blk16, 0, stream>>>(nullptr, Bmsg, msg, PRB[l], N_EDGES, C, F3, 0, C, C,
                                          0, 0, 0, xin, F, srcp, dstp, edge_attr, EWv[l], EBv[l]);

    // aggregation -> agg [N][4][4F]
    long long tot = (long long)N_NODES * C;
    aggregate_k<<<(int)((tot + 255) / 256), 256, 0, stream>>>(msg, row_ptr, eids, agg, F);

    // P[n][t][54] = agg_t @ Wcat_t   (batched over towers; P aliases msg)
    dim3 gp((N_NODES + 63) / 64, 1, 4);
    gemm64_k<0><<<gp, blk16, 0, stream>>>(agg, Wcat, Pbuf, nullptr, N_NODES, 54, F4, 16 * F, 54,
                                          216, 4 * F, (long long)F4 * 54, 54, nullptr, 0, nullptr,
                                          nullptr, nullptr, nullptr, nullptr);

    // y0 = x @ W0cat + pob
    dim3 gx((N_NODES + 63) / 64, 2, 1);
    gemm64_k<0><<<gx, blk16, 0, stream>>>(xin, W0cat, y0, POB[l], N_NODES, 72, F, F, 72, 72, 0, 0,
                                          0, nullptr, 0, nullptr, nullptr, nullptr, nullptr,
                                          nullptr);

    // y0 += P combined with amp scalers
    combine_k<<<(N_NODES * 72 + 255) / 256, 256, 0, stream>>>(y0, Pbuf, amp);

    // y1 = y0 @ lw + lb
    gemm64_k<0><<<gx, blk16, 0, stream>>>(y0, LWv[l], y1, LBv[l], N_NODES, 72, 72, 72, 72, 72, 0,
                                          0, 0, nullptr, 0, nullptr, nullptr, nullptr, nullptr,
                                          nullptr);

    // BN + ReLU
    hipMemsetAsync(bnsums, 0, 144 * 8, stream);
    bnstats_k<<<40, 288, 0, stream>>>(y1, bnsums);
    bnrelu_k<<<(N_NODES * 72 + 255) / 256, 256, 0, stream>>>(y1, bnsums, Gv[l], BEv[l], xout);

    xin = xout;
  }

  // global add pool (layer 3 output is in xB)
  pool_k<<<(N_NODES * 72 + 255) / 256, 256, 0, stream>>>(xB, batch, gpool);

  // MLP heads + final assembly
  heads_k<<<3, 512, 0, stream>>>(gpool, heads[0], heads[1], heads[2], (float*)d_out);
}

// Round 2
// 1198.283 us; speedup vs baseline: 1.6108x; 1.6108x over previous
//
#include <hip/hip_runtime.h>
#include <math.h>
#include <cstdint>

#define N_NODES 20000
#define N_EDGES 60000
#define N_GRAPHS 512
#define NT 4

// ---------------- CSR build ----------------
__global__ void count_deg_k(const int* __restrict__ dst, int* __restrict__ deg) {
  int e = blockIdx.x * blockDim.x + threadIdx.x;
  if (e < N_EDGES) atomicAdd(&deg[dst[e]], 1);
}

__global__ void scan_rowptr_k(const int* __restrict__ deg, int* __restrict__ rp) {
  __shared__ int ss[1024];
  int tid = threadIdx.x;
  const int per = (N_NODES + 1023) / 1024;  // 20
  int base = tid * per;
  int s = 0;
  for (int i = 0; i < per; i++) { int idx = base + i; if (idx < N_NODES) s += deg[idx]; }
  ss[tid] = s;
  __syncthreads();
  for (int off = 1; off < 1024; off <<= 1) {
    int v = (tid >= off) ? ss[tid - off] : 0;
    __syncthreads();
    ss[tid] += v;
    __syncthreads();
  }
  int run = ss[tid] - s;  // exclusive prefix
  for (int i = 0; i < per; i++) {
    int idx = base + i;
    if (idx < N_NODES) { rp[idx] = run; run += deg[idx]; }
  }
  if (tid == 0) rp[N_NODES] = ss[1023];
}

__global__ void fill_csr_k(const int* __restrict__ dst, const int* __restrict__ rp,
                           int* __restrict__ cur, int* __restrict__ eids) {
  int e = blockIdx.x * blockDim.x + threadIdx.x;
  if (e < N_EDGES) {
    int d = dst[e];
    int pos = atomicAdd(&cur[d], 1);
    eids[rp[d] + pos] = e;
  }
}

__global__ void amp_k(const int* __restrict__ deg, float* __restrict__ amp, float adl) {
  int n = blockIdx.x * blockDim.x + threadIdx.x;
  if (n < N_NODES) {
    float d = (float)(deg[n] > 0 ? deg[n] : 1);
    amp[n] = logf(d + 1.0f) / adl;
  }
}

// ---------------- SGEMM: 128x64 tile, 256 threads, 8x4 micro ----------------
// C[M,N] = A[M,K](lda) @ B[K,N](ldb) + bias. nb: B physical col guard (mult of 4).
// ns: store col guard (mult of 4; may exceed N into padded cols).
template <int AVEC>
__global__ __launch_bounds__(256, 2) void sgemm_k(
    const float* __restrict__ A, const float* __restrict__ B, float* __restrict__ C,
    const float* __restrict__ bias, int M, int N, int K, int lda, int ldb, int ldc,
    int nb, int ns, long long bsA, long long bsB, long long bsC) {
  __shared__ float As[16][128];
  __shared__ float Bs[16][64];
  const int tid = threadIdx.x;
  const int tx = tid & 15, ty = tid >> 4;
  const int m0 = blockIdx.x * 128, n0 = blockIdx.y * 64;
  const int z = blockIdx.z;
  A += bsA * z; B += bsB * z; C += bsC * z;

  float acc[8][4] = {};
  for (int k0 = 0; k0 < K; k0 += 16) {
    if (AVEC) {
#pragma unroll
      for (int it = 0; it < 2; ++it) {
        int u = it * 256 + tid;
        int row = u >> 2, q = u & 3;
        int gm = m0 + row, gk = k0 + 4 * q;
        float4 v = make_float4(0.f, 0.f, 0.f, 0.f);
        if (gm < M && gk < K) v = *(const float4*)&A[(long long)gm * lda + gk];
        As[4 * q + 0][row] = v.x;
        As[4 * q + 1][row] = v.y;
        As[4 * q + 2][row] = v.z;
        As[4 * q + 3][row] = v.w;
      }
    } else {
#pragma unroll
      for (int it = 0; it < 8; ++it) {
        int u = it * 256 + tid;
        int row = u >> 4, kk = u & 15;
        int gm = m0 + row, gk = k0 + kk;
        As[kk][row] = (gm < M && gk < K) ? A[(long long)gm * lda + gk] : 0.f;
      }
    }
    {
      int kk = tid >> 4, n4 = (tid & 15) * 4;
      int gk = k0 + kk, gn = n0 + n4;
      float4 v = make_float4(0.f, 0.f, 0.f, 0.f);
      if (gk < K && gn < nb) v = *(const float4*)&B[(long long)gk * ldb + gn];
      *(float4*)&Bs[kk][n4] = v;
    }
    __syncthreads();
#pragma unroll
    for (int kk = 0; kk < 16; ++kk) {
      float a[8], b[4];
#pragma unroll
      for (int i = 0; i < 8; i++) a[i] = As[kk][ty * 8 + i];
#pragma unroll
      for (int j = 0; j < 4; j++) b[j] = Bs[kk][tx * 4 + j];
#pragma unroll
      for (int i = 0; i < 8; i++)
#pragma unroll
        for (int j = 0; j < 4; j++) acc[i][j] += a[i] * b[j];
    }
    __syncthreads();
  }
  int gn = n0 + tx * 4;
  if (gn < ns) {
    float b0 = 0.f, b1 = 0.f, b2 = 0.f, b3 = 0.f;
    if (bias) {
      b0 = bias[gn]; b1 = bias[gn + 1]; b2 = bias[gn + 2]; b3 = bias[gn + 3];
    }
#pragma unroll
    for (int i = 0; i < 8; i++) {
      int gm = m0 + ty * 8 + i;
      if (gm >= M) continue;
      float4 v;
      v.x = acc[i][0] + b0; v.y = acc[i][1] + b1;
      v.z = acc[i][2] + b2; v.w = acc[i][3] + b3;
      *(float4*)&C[(long long)gm * ldc + gn] = v;
    }
  }
}

// ---------------- fused PNA aggregation ----------------
// m'[e][c] = Xs[src[e]][c] + ea[e]@Wec[:,c] + bec[c];  msg = Xd[dst] + m'
// mean/min/max shift by Xd[n]; std invariant. deg==0: all 0, std=sqrt(eps).
__global__ void agg_fused_k(const float* __restrict__ XdXs, const float* __restrict__ ea,
                            const int* __restrict__ srcI, const int* __restrict__ rp,
                            const int* __restrict__ eids, const float* __restrict__ Wec,
                            const float* __restrict__ bec, float* __restrict__ agg, int F) {
  const int C = 4 * F;
  long long idx = (long long)blockIdx.x * blockDim.x + threadIdx.x;
  if (idx >= (long long)N_NODES * C) return;
  int n = (int)(idx / C), c = (int)(idx % C);
  int s = rp[n], e = rp[n + 1];
  float w0 = Wec[c], w1 = Wec[C + c], w2 = Wec[2 * C + c], bc = bec[c];
  float sum = 0.f, sq = 0.f, mn = INFINITY, mx = -INFINITY;
  for (int i = s; i < e; i++) {
    int eid = eids[i];
    int sr = srcI[eid];
    float v = XdXs[(long long)sr * 2 * C + C + c] + ea[eid * 3 + 0] * w0 +
              ea[eid * 3 + 1] * w1 + ea[eid * 3 + 2] * w2 + bc;
    sum += v; sq += v * v;
    mn = fminf(mn, v); mx = fmaxf(mx, v);
  }
  int t = c / F, f = c % F;
  long long base = (long long)n * 4 * C + (long long)t * 4 * F;
  float mean, stdv;
  if (e == s) {
    mean = 0.f; mn = 0.f; mx = 0.f; stdv = sqrtf(1e-5f);
  } else {
    float inv = 1.f / (float)(e - s);
    float xd = XdXs[(long long)n * 2 * C + c];
    float mu = sum * inv;
    float var = sq * inv - mu * mu;
    if (var < 0.f) var = 0.f;
    stdv = sqrtf(var + 1e-5f);
    mean = xd + mu; mn += xd; mx += xd;
  }
  agg[base + f] = mean;
  agg[base + F + f] = mn;
  agg[base + 2 * F + f] = mx;
  agg[base + 3 * F + f] = stdv;
}

// ---------------- weight repacks ----------------
// Bm [F][8F]: cols<4F: Wd (prw row f), cols>=4F: Ws (prw row F+f)
// Wc [4][4F][64]: cols<54 from pow rows {F+j,5F+j,9F+j}; pad 0
// W0 [F][72]; Wec [3][4F] = ew @ We_sub; bec [4F] = eb @ We_sub + prb
__global__ void repack2_k(const float* __restrict__ prw, const float* __restrict__ pw,
                          const float* __restrict__ ew, const float* __restrict__ eb,
                          const float* __restrict__ prb, float* __restrict__ Bm,
                          float* __restrict__ Wc, float* __restrict__ W0,
                          float* __restrict__ Wec, float* __restrict__ bec, int F) {
  const int C = 4 * F, F3 = 3 * F, F8 = 8 * F;
  const int nBm = F * F8, nWc = 4 * C * 64, nW0 = F * 72, nWec = 3 * C, nbec = C;
  int idx = blockIdx.x * blockDim.x + threadIdx.x;
  if (idx < nBm) {
    int f = idx / F8, c = idx % F8;
    int cc = (c < C) ? c : (c - C);
    int t = cc / F, o = cc % F;
    int row = (c < C) ? f : (F + f);
    Bm[idx] = prw[((long long)t * F3 + row) * F + o];
  } else if (idx < nBm + nWc) {
    int j2 = idx - nBm;
    int t = j2 / (C * 64);
    int rem = j2 % (C * 64);
    int j = rem / 64, col = rem % 64;
    float v = 0.f;
    if (col < 54) {
      int seg = col / 18, o = col % 18;
      int row = (seg == 0) ? (F + j) : ((seg == 1) ? (5 * F + j) : (9 * F + j));
      v = pw[((long long)t * 13 * F + row) * 18 + o];
    }
    Wc[j2] = v;
  } else if (idx < nBm + nWc + nW0) {
    int j2 = idx - nBm - nWc;
    int f = j2 / 72, c = j2 % 72;
    int t = c / 18, o = c % 18;
    W0[j2] = pw[((long long)t * 13 * F + f) * 18 + o];
  } else if (idx < nBm + nWc + nW0 + nWec) {
    int j2 = idx - nBm - nWc - nW0;
    int r = j2 / C, c = j2 % C;
    int t = c / F, o = c % F;
    float s = 0.f;
    for (int f = 0; f < F; f++) s += ew[r * F + f] * prw[((long long)t * F3 + 2 * F + f) * F + o];
    Wec[j2] = s;
  } else if (idx < nBm + nWc + nW0 + nWec + nbec) {
    int c = idx - (nBm + nWc + nW0 + nWec);
    int t = c / F, o = c % F;
    float s = prb[t * F + o];
    for (int f = 0; f < F; f++) s += eb[f] * prw[((long long)t * F3 + 2 * F + f) * F + o];
    bec[c] = s;
  }
}

// y0[n][t*18+o] += P[n][t*56+o] + amp*P[..+18+o] + P[..+36+o]/amp  (P ldc=224)
__global__ void combine_k(float* __restrict__ y0, const float* __restrict__ P,
                          const float* __restrict__ amp) {
  int idx = blockIdx.x * blockDim.x + threadIdx.x;
  if (idx >= N_NODES * 72) return;
  int n = idx / 72, c = idx % 72;
  int t = c / 18, o = c % 18;
  float a = amp[n];
  const float* p = P + (long long)n * 224 + t * 56;
  y0[idx] += p[o] + a * p[18 + o] + p[36 + o] / a;
}

// ---------------- BatchNorm over nodes ----------------
__global__ void bnstats_k(const float* __restrict__ y, double* __restrict__ sums) {
  int c = threadIdx.x % 72;
  int q = threadIdx.x / 72;
  __shared__ float ps[288], pq[288];
  int rows_per_block = (N_NODES + gridDim.x - 1) / gridDim.x;
  int r0 = blockIdx.x * rows_per_block;
  int r1 = r0 + rows_per_block;
  if (r1 > N_NODES) r1 = N_NODES;
  float s = 0.f, sq = 0.f;
  for (int r = r0 + q; r < r1; r += 4) {
    float v = y[(long long)r * 72 + c];
    s += v; sq += v * v;
  }
  ps[threadIdx.x] = s; pq[threadIdx.x] = sq;
  __syncthreads();
  if (q == 0) {
    s = ps[c] + ps[72 + c] + ps[144 + c] + ps[216 + c];
    sq = pq[c] + pq[72 + c] + pq[144 + c] + pq[216 + c];
    atomicAdd(&sums[c], (double)s);
    atomicAdd(&sums[72 + c], (double)sq);
  }
}

__global__ void bnrelu_k(const float* __restrict__ y, const double* __restrict__ sums,
                         const float* __restrict__ g, const float* __restrict__ be,
                         float* __restrict__ out) {
  int idx = blockIdx.x * blockDim.x + threadIdx.x;
  if (idx >= N_NODES * 72) return;
  int c = idx % 72;
  double mud = sums[c] / (double)N_NODES;
  double vard = sums[72 + c] / (double)N_NODES - mud * mud;
  if (vard < 0.0) vard = 0.0;
  float scale = g[c] / sqrtf((float)vard + 1e-5f);
  float shift = be[c] - (float)mud * scale;
  float v = y[idx] * scale + shift;
  out[idx] = v > 0.f ? v : 0.f;
}

// ---------------- pooling (transposed output [72][512]) ----------------
__global__ void pool_k(const float* __restrict__ h, const int* __restrict__ batch,
                       float* __restrict__ gpT) {
  int idx = blockIdx.x * blockDim.x + threadIdx.x;
  if (idx >= N_NODES * 72) return;
  int n = idx / 72, c = idx % 72;
  atomicAdd(&gpT[c * N_GRAPHS + batch[n]], h[idx]);
}

// ---------------- MLP heads, column-parallel ----------------
struct HeadP {
  const float *w1, *b1, *g1, *be1, *w2, *b2, *g2, *be2, *w3, *b3;
};

__device__ inline float wred(float v) {
#pragma unroll
  for (int off = 32; off > 0; off >>= 1) v += __shfl_xor(v, off);
  return v;
}

// Layer1: h1T[head][o][r] = relu(BN(gpT@w1+b1)) ; grid = 3*50 blocks x 512
__global__ __launch_bounds__(512) void head_l1_k(const float* __restrict__ gpT, HeadP hA,
                                                 HeadP hB, HeadP hC, float* __restrict__ h1T) {
  int head = blockIdx.x / 50, o = blockIdx.x % 50;
  HeadP hp = (head == 0) ? hA : ((head == 1) ? hB : hC);
  int r = threadIdx.x, lane = r & 63, wave = r >> 6;
  __shared__ float rs[8], rq[8], sc_sh, sh_sh;
  float acc = hp.b1[o];
  for (int k = 0; k < 72; k++) acc += gpT[k * N_GRAPHS + r] * hp.w1[k * 50 + o];
  float s = wred(acc), q = wred(acc * acc);
  if (lane == 0) { rs[wave] = s; rq[wave] = q; }
  __syncthreads();
  if (r == 0) {
    float ts = 0.f, tq = 0.f;
#pragma unroll
    for (int i = 0; i < 8; i++) { ts += rs[i]; tq += rq[i]; }
    float mu = ts / (float)N_GRAPHS;
    float var = tq / (float)N_GRAPHS - mu * mu;
    if (var < 0.f) var = 0.f;
    float sc = hp.g1[o] / sqrtf(var + 1e-5f);
    sc_sh = sc; sh_sh = hp.be1[o] - mu * sc;
  }
  __syncthreads();
  float v = acc * sc_sh + sh_sh;
  h1T[(head * 50 + o) * N_GRAPHS + r] = v > 0.f ? v : 0.f;
}

// Layer2: h2T[head][o][r] ; grid = 3*25 blocks x 512
__global__ __launch_bounds__(512) void head_l2_k(const float* __restrict__ h1T, HeadP hA,
                                                 HeadP hB, HeadP hC, float* __restrict__ h2T) {
  int head = blockIdx.x / 25, o = blockIdx.x % 25;
  HeadP hp = (head == 0) ? hA : ((head == 1) ? hB : hC);
  int r = threadIdx.x, lane = r & 63, wave = r >> 6;
  __shared__ float rs[8], rq[8], sc_sh, sh_sh;
  float acc = hp.b2[o];
  const float* hb = h1T + head * 50 * N_GRAPHS;
  for (int k = 0; k < 50; k++) acc += hb[k * N_GRAPHS + r] * hp.w2[k * 25 + o];
  float s = wred(acc), q = wred(acc * acc);
  if (lane == 0) { rs[wave] = s; rq[wave] = q; }
  __syncthreads();
  if (r == 0) {
    float ts = 0.f, tq = 0.f;
#pragma unroll
    for (int i = 0; i < 8; i++) { ts += rs[i]; tq += rq[i]; }
    float mu = ts / (float)N_GRAPHS;
    float var = tq / (float)N_GRAPHS - mu * mu;
    if (var < 0.f) var = 0.f;
    float sc = hp.g2[o] / sqrtf(var + 1e-5f);
    sc_sh = sc; sh_sh = hp.be2[o] - mu * sc;
  }
  __syncthreads();
  float v = acc * sc_sh + sh_sh;
  h2T[(head * 25 + o) * N_GRAPHS + r] = v > 0.f ? v : 0.f;
}

// Layer3 + assembly ; grid = 3 blocks x 512
__global__ __launch_bounds__(512) void head_l3_k(const float* __restrict__ h2T, HeadP hA,
                                                 HeadP hB, HeadP hC, float* __restrict__ out) {
  int head = blockIdx.x;
  HeadP hp = (head == 0) ? hA : ((head == 1) ? hB : hC);
  int r = threadIdx.x;
  int od = (head == 0) ? 3 : 7;
  float acc3[7];
#pragma unroll
  for (int o = 0; o < 7; o++) acc3[o] = (o < od) ? hp.b3[o] : 0.f;
  const float* hb = h2T + head * 25 * N_GRAPHS;
  for (int k = 0; k < 25; k++) {
    float hv = hb[k * N_GRAPHS + r];
#pragma unroll
    for (int o = 0; o < 7; o++)
      if (o < od) acc3[o] += hv * hp.w3[k * od + o];
  }
  float* og = out + r * 20;  // [512][2][10]
  if (head == 0) {
#pragma unroll
    for (int j = 0; j < 3; j++) {
      float v = tanhf(acc3[j]);
      og[7 + j] = v;
      og[17 + j] = v;
    }
  } else {
    const float unit[7] = {1.f, 1.f, 100.f, 0.01f, 1000.f, 0.f, 1e-5f};
    int base = (head == 1) ? 0 : 10;
#pragma unroll
    for (int j = 0; j < 7; j++) {
      float v = acc3[j];
      v = v > 0.f ? v : 0.f;
      og[base + j] = v + unit[j];
    }
  }
}

// ---------------- host launch ----------------
static inline char* alignp(char* p, size_t a) {
  return (char*)(((uintptr_t)p + (a - 1)) & ~(uintptr_t)(a - 1));
}

extern "C" void kernel_launch(void* const* d_in, const int* in_sizes, int n_in, void* d_out,
                              int out_size, void* d_ws, size_t ws_size, hipStream_t stream) {
  const float* x = (const float*)d_in[0];
  const float* edge_attr = (const float*)d_in[1];
  const int* srcp = (const int*)d_in[2];
  const int* dstp = srcp + N_EDGES;
  const int* batch = (const int*)d_in[3];

  const float *EWv[4], *EBv[4], *PRW[4], *PRB[4], *PW[4], *POB[4], *LWv[4], *LBv[4], *Gv[4],
      *BEv[4];
  EWv[0] = (const float*)d_in[4];  EBv[0] = (const float*)d_in[5];
  PRW[0] = (const float*)d_in[6];  PRB[0] = (const float*)d_in[7];
  PW[0] = (const float*)d_in[8];   POB[0] = (const float*)d_in[9];
  LWv[0] = (const float*)d_in[10]; LBv[0] = (const float*)d_in[11];
  Gv[0] = (const float*)d_in[12];  BEv[0] = (const float*)d_in[13];
  const float* cs_ew = (const float*)d_in[14];
  const float* cs_eb = (const float*)d_in[15];
  const float* cs_prw = (const float*)d_in[16];
  const float* cs_prb = (const float*)d_in[17];
  const float* cs_pow = (const float*)d_in[18];
  const float* cs_pob = (const float*)d_in[19];
  const float* cs_lw = (const float*)d_in[20];
  const float* cs_lb = (const float*)d_in[21];
  const float* cs_g = (const float*)d_in[22];
  const float* cs_be = (const float*)d_in[23];
  for (int i = 1; i < 4; i++) {
    int j = i - 1;
    EWv[i] = cs_ew + j * 3 * 72;        EBv[i] = cs_eb + j * 72;
    PRW[i] = cs_prw + j * 4 * 216 * 72; PRB[i] = cs_prb + j * 4 * 72;
    PW[i] = cs_pow + j * 4 * 936 * 18;  POB[i] = cs_pob + j * 4 * 18;
    LWv[i] = cs_lw + j * 72 * 72;       LBv[i] = cs_lb + j * 72;
    Gv[i] = cs_g + j * 72;              BEv[i] = cs_be + j * 72;
  }
  HeadP heads[3];
  for (int m = 0; m < 3; m++) {
    const float** pp = (const float**)&heads[m];
    for (int k = 0; k < 10; k++) pp[k] = (const float*)d_in[24 + m * 10 + k];
  }

  // workspace carve
  char* p = (char*)d_ws;
  int* deg_i = (int*)p;   p += N_NODES * 4;
  int* cursor = (int*)p;  p += N_NODES * 4;
  int* row_ptr = (int*)p; p += (N_NODES + 1) * 4;
  int* eids = (int*)p;    p += N_EDGES * 4;
  p = alignp(p, 256);
  float* amp = (float*)p; p += N_NODES * 4;
  p = alignp(p, 256);
  // region R: XdXs [20000][576]; later aliased by P / y0 / y1
  float* R = (float*)p;   p += (size_t)N_NODES * 576 * 4;
  float* XdXs = R;
  float* Pp = R;                          // [20000][224]  (XdXs dead by then)
  float* y0 = R + (size_t)N_NODES * 224;  // [20000][72]
  float* y1 = y0 + (size_t)N_NODES * 72;  // [20000][72]
  p = alignp(p, 256);
  float* agg = (float*)p; p += (size_t)N_NODES * 1152 * 4;
  p = alignp(p, 256);
  float* Bm = (float*)p;  p += 72 * 576 * 4;
  float* Wc = (float*)p;  p += 4 * 288 * 64 * 4;
  float* W0 = (float*)p;  p += 72 * 72 * 4;
  float* Wec = (float*)p; p += 3 * 288 * 4;
  float* bec = (float*)p; p += 288 * 4;
  p = alignp(p, 256);
  float* xA = (float*)p;  p += (size_t)N_NODES * 72 * 4;
  float* xB = (float*)p;  p += (size_t)N_NODES * 72 * 4;
  p = alignp(p, 256);
  double* bnsums = (double*)p; p += 144 * 8;
  p = alignp(p, 256);
  float* gpT = (float*)p;  p += 72 * N_GRAPHS * 4;
  float* h1T = (float*)p;  p += 3 * 50 * N_GRAPHS * 4;
  float* h2T = (float*)p;  p += 3 * 25 * N_GRAPHS * 4;
  (void)ws_size; (void)n_in; (void)in_sizes; (void)out_size;

  static const double hist[7] = {67167, 3157428, 5106064, 885236, 453935, 0, 11152};
  double num = 0, den = 0;
  for (int i = 0; i < 7; i++) { num += log((double)(i + 1)) * hist[i]; den += hist[i]; }
  float adl = (float)(num / den);

  // CSR + amp
  hipMemsetAsync(deg_i, 0, 2 * N_NODES * 4, stream);
  hipMemsetAsync(gpT, 0, 72 * N_GRAPHS * 4, stream);
  count_deg_k<<<(N_EDGES + 255) / 256, 256, 0, stream>>>(dstp, deg_i);
  scan_rowptr_k<<<1, 1024, 0, stream>>>(deg_i, row_ptr);
  fill_csr_k<<<(N_EDGES + 255) / 256, 256, 0, stream>>>(dstp, row_ptr, cursor, eids);
  amp_k<<<(N_NODES + 255) / 256, 256, 0, stream>>>(deg_i, amp, adl);

  const int gM = (N_NODES + 127) / 128;  // 157
  const float* xin = x;
  for (int l = 0; l < 4; l++) {
    const int F = (l == 0) ? 9 : 72;
    const int C = 4 * F, F8 = 8 * F;
    float* xout = (l & 1) ? xB : xA;

    int nrep = F * F8 + 4 * C * 64 + F * 72 + 3 * C + C;
    repack2_k<<<(nrep + 255) / 256, 256, 0, stream>>>(PRW[l], PW[l], EWv[l], EBv[l], PRB[l], Bm,
                                                      Wc, W0, Wec, bec, F);

    // XdXs = xin @ [Wd|Ws]  : M=20000, N=8F, K=F
    {
      dim3 g(gM, (F8 + 63) / 64, 1);
      if (F % 4 == 0)
        sgemm_k<1><<<g, 256, 0, stream>>>(xin, Bm, XdXs, nullptr, N_NODES, F8, F, F, F8, F8, F8,
                                          F8, 0, 0, 0);
      else
        sgemm_k<0><<<g, 256, 0, stream>>>(xin, Bm, XdXs, nullptr, N_NODES, F8, F, F, F8, F8, F8,
                                          F8, 0, 0, 0);
    }

    // fused aggregation -> agg [N][4C]
    {
      long long tot = (long long)N_NODES * C;
      agg_fused_k<<<(int)((tot + 255) / 256), 256, 0, stream>>>(XdXs, edge_attr, srcp, row_ptr,
                                                                eids, Wec, bec, agg, F);
    }

    // P[n][t*56+col] = agg_t @ Wc_t : M=20000, N=54(store 56), K=4F, z=4
    {
      dim3 g(gM, 1, 4);
      sgemm_k<1><<<g, 256, 0, stream>>>(agg, Wc, Pp, nullptr, N_NODES, 54, C, 4 * C, 64, 224, 64,
                                        56, C, (long long)C * 64, 56);
    }

    // y0 = xin @ W0 + pob : N=72, K=F
    {
      dim3 g(gM, 2, 1);
      if (F % 4 == 0)
        sgemm_k<1><<<g, 256, 0, stream>>>(xin, W0, y0, POB[l], N_NODES, 72, F, F, 72, 72, 72, 72,
                                          0, 0, 0);
      else
        sgemm_k<0><<<g, 256, 0, stream>>>(xin, W0, y0, POB[l], N_NODES, 72, F, F, 72, 72, 72, 72,
                                          0, 0, 0);
    }

    combine_k<<<(N_NODES * 72 + 255) / 256, 256, 0, stream>>>(y0, Pp, amp);

    // y1 = y0 @ lw + lb
    {
      dim3 g(gM, 2, 1);
      sgemm_k<1><<<g, 256, 0, stream>>>(y0, LWv[l], y1, LBv[l], N_NODES, 72, 72, 72, 72, 72, 72,
                                        72, 0, 0, 0);
    }

    hipMemsetAsync(bnsums, 0, 144 * 8, stream);
    bnstats_k<<<40, 288, 0, stream>>>(y1, bnsums);
    bnrelu_k<<<(N_NODES * 72 + 255) / 256, 256, 0, stream>>>(y1, bnsums, Gv[l], BEv[l], xout);

    xin = xout;
  }

  // pool (layer 3 output in xB) -> gpT [72][512]
  pool_k<<<(N_NODES * 72 + 255) / 256, 256, 0, stream>>>(xB, batch, gpT);

  head_l1_k<<<150, 512, 0, stream>>>(gpT, heads[0], heads[1], heads[2], h1T);
  head_l2_k<<<75, 512, 0, stream>>>(h1T, heads[0], heads[1], heads[2], h2T);
  head_l3_k<<<3, 512, 0, stream>>>(h2T, heads[0], heads[1], heads[2], (float*)d_out);
}

// Round 7
// 940.923 us; speedup vs baseline: 2.0514x; 1.2735x over previous
//
#include <hip/hip_runtime.h>
#include <math.h>
#include <cstdint>

#define N_NODES 20000
#define N_EDGES 60000
#define N_GRAPHS 512
#define NT 4

// ---------------- CSR build ----------------
__global__ void count_deg_k(const int* __restrict__ dst, int* __restrict__ deg) {
  int e = blockIdx.x * blockDim.x + threadIdx.x;
  if (e < N_EDGES) atomicAdd(&deg[dst[e]], 1);
}

__global__ void scan_rowptr_k(const int* __restrict__ deg, int* __restrict__ rp) {
  __shared__ int ss[1024];
  int tid = threadIdx.x;
  const int per = (N_NODES + 1023) / 1024;  // 20
  int base = tid * per;
  int s = 0;
  for (int i = 0; i < per; i++) { int idx = base + i; if (idx < N_NODES) s += deg[idx]; }
  ss[tid] = s;
  __syncthreads();
  for (int off = 1; off < 1024; off <<= 1) {
    int v = (tid >= off) ? ss[tid - off] : 0;
    __syncthreads();
    ss[tid] += v;
    __syncthreads();
  }
  int run = ss[tid] - s;  // exclusive prefix
  for (int i = 0; i < per; i++) {
    int idx = base + i;
    if (idx < N_NODES) { rp[idx] = run; run += deg[idx]; }
  }
  if (tid == 0) rp[N_NODES] = ss[1023];
}

__global__ void fill_csr_k(const int* __restrict__ dst, const int* __restrict__ rp,
                           int* __restrict__ cur, int* __restrict__ eids) {
  int e = blockIdx.x * blockDim.x + threadIdx.x;
  if (e < N_EDGES) {
    int d = dst[e];
    int pos = atomicAdd(&cur[d], 1);
    eids[rp[d] + pos] = e;
  }
}

__global__ void amp_k(const int* __restrict__ deg, float* __restrict__ amp, float adl) {
  int n = blockIdx.x * blockDim.x + threadIdx.x;
  if (n < N_NODES) {
    float d = (float)(deg[n] > 0 ? deg[n] : 1);
    amp[n] = logf(d + 1.0f) / adl;
  }
}

// graph boundaries from sorted batch: grp[g] = first node with batch >= g
__global__ void gboundary_k(const int* __restrict__ batch, int* __restrict__ grp) {
  int n = blockIdx.x * blockDim.x + threadIdx.x;
  if (n >= N_NODES) return;
  int bn = batch[n];
  int bp = (n == 0) ? -1 : batch[n - 1];
  for (int g = bp + 1; g <= bn; g++) grp[g] = n;
  if (n == N_NODES - 1)
    for (int g = bn + 1; g <= N_GRAPHS; g++) grp[g] = N_NODES;
}

// ---------------- SGEMM: 128x64 tile, 256 threads, 8x4 micro ----------------
// BNA: apply v=relu(v*vsc[k]+vsh[k]) to A elements on load.
// EPI=0: C store (+bias). EPI=1: PNA-combine epilogue -> y0 += (no C store).
// EPI=2: C store (+bias) then BN column stats -> double atomics into bnsums.
template <int AVEC, int BNA, int EPI>
__global__ __launch_bounds__(256, 2) void sgemm2_k(
    const float* __restrict__ A, const float* __restrict__ B, float* __restrict__ C,
    const float* __restrict__ bias, int M, int N, int K, int lda, int ldb, int ldc,
    int nb, int ns, long long bsA, long long bsB,
    const float* __restrict__ vsc, const float* __restrict__ vsh,
    const float* __restrict__ amp, float* __restrict__ y0, int ldy,
    double* __restrict__ bnsums) {
  constexpr int SM = (EPI == 1) ? 128 * 57 : (16 * 128 + 16 * 64);
  __shared__ float smem[SM];
  float(*As)[128] = (float(*)[128])smem;
  float(*Bs)[64] = (float(*)[64])(smem + 16 * 128);

  const int tid = threadIdx.x;
  const int tx = tid & 15, ty = tid >> 4;
  const int m0 = blockIdx.x * 128, n0 = blockIdx.y * 64;
  const int z = blockIdx.z;
  A += bsA * z; B += bsB * z;

  float acc[8][4] = {};
  for (int k0 = 0; k0 < K; k0 += 16) {
    if (AVEC) {
#pragma unroll
      for (int it = 0; it < 2; ++it) {
        int u = it * 256 + tid;
        int row = u >> 2, q = u & 3;
        int gm = m0 + row, gk = k0 + 4 * q;
        float4 v = make_float4(0.f, 0.f, 0.f, 0.f);
        if (gm < M && gk < K) {
          v = *(const float4*)&A[(long long)gm * lda + gk];
          if (BNA) {
            float4 sc = *(const float4*)&vsc[gk];
            float4 sh = *(const float4*)&vsh[gk];
            v.x = fmaxf(v.x * sc.x + sh.x, 0.f);
            v.y = fmaxf(v.y * sc.y + sh.y, 0.f);
            v.z = fmaxf(v.z * sc.z + sh.z, 0.f);
            v.w = fmaxf(v.w * sc.w + sh.w, 0.f);
          }
        }
        As[4 * q + 0][row] = v.x;
        As[4 * q + 1][row] = v.y;
        As[4 * q + 2][row] = v.z;
        As[4 * q + 3][row] = v.w;
      }
    } else {
#pragma unroll
      for (int it = 0; it < 8; ++it) {
        int u = it * 256 + tid;
        int row = u >> 4, kk = u & 15;
        int gm = m0 + row, gk = k0 + kk;
        float v = 0.f;
        if (gm < M && gk < K) {
          v = A[(long long)gm * lda + gk];
          if (BNA) v = fmaxf(v * vsc[gk] + vsh[gk], 0.f);
        }
        As[kk][row] = v;
      }
    }
    {
      int kk = tid >> 4, n4 = (tid & 15) * 4;
      int gk = k0 + kk, gn = n0 + n4;
      float4 v = make_float4(0.f, 0.f, 0.f, 0.f);
      if (gk < K && gn < nb) v = *(const float4*)&B[(long long)gk * ldb + gn];
      *(float4*)&Bs[kk][n4] = v;
    }
    __syncthreads();
#pragma unroll
    for (int kk = 0; kk < 16; ++kk) {
      float a[8], b[4];
#pragma unroll
      for (int i = 0; i < 8; i++) a[i] = As[kk][ty * 8 + i];
#pragma unroll
      for (int j = 0; j < 4; j++) b[j] = Bs[kk][tx * 4 + j];
#pragma unroll
      for (int i = 0; i < 8; i++)
#pragma unroll
        for (int j = 0; j < 4; j++) acc[i][j] += a[i] * b[j];
    }
    __syncthreads();
  }

  if (EPI == 1) {
    // stage P tile into LDS, combine identity/amp/atten into y0 columns
    float(*Ps)[57] = (float(*)[57])smem;
    int c0 = tx * 4;
#pragma unroll
    for (int i = 0; i < 8; i++) {
      if (c0 < 56) {
#pragma unroll
        for (int j = 0; j < 4; j++) Ps[ty * 8 + i][c0 + j] = acc[i][j];
      }
    }
    __syncthreads();
#pragma unroll
    for (int it = 0; it < 9; ++it) {
      int item = it * 256 + tid;
      int r = item / 18, o = item - r * 18;
      int gm = m0 + r;
      if (gm < M) {
        float a = amp[gm];
        float v = Ps[r][o] + a * Ps[r][18 + o] + Ps[r][36 + o] / a;
        y0[(long long)gm * ldy + z * 18 + o] += v;
      }
    }
    return;
  }

  int gn = n0 + tx * 4;
  float cs[4] = {0.f, 0.f, 0.f, 0.f}, cq[4] = {0.f, 0.f, 0.f, 0.f};
  if (gn < ns) {
    float b0 = 0.f, b1 = 0.f, b2 = 0.f, b3 = 0.f;
    if (bias) { b0 = bias[gn]; b1 = bias[gn + 1]; b2 = bias[gn + 2]; b3 = bias[gn + 3]; }
#pragma unroll
    for (int i = 0; i < 8; i++) {
      int gm = m0 + ty * 8 + i;
      if (gm >= M) continue;
      float4 v;
      v.x = acc[i][0] + b0; v.y = acc[i][1] + b1;
      v.z = acc[i][2] + b2; v.w = acc[i][3] + b3;
      *(float4*)&C[(long long)gm * ldc + gn] = v;
      if (EPI == 2) {
        cs[0] += v.x; cs[1] += v.y; cs[2] += v.z; cs[3] += v.w;
        cq[0] += v.x * v.x; cq[1] += v.y * v.y; cq[2] += v.z * v.z; cq[3] += v.w * v.w;
      }
    }
  }
  if (EPI == 2) {
    __syncthreads();
    float* psum = smem;          // [16][64]
    float* psq = smem + 1024;    // [16][64]
#pragma unroll
    for (int j = 0; j < 4; j++) {
      psum[ty * 64 + tx * 4 + j] = cs[j];
      psq[ty * 64 + tx * 4 + j] = cq[j];
    }
    __syncthreads();
    if (tid < 64) {
      float s = 0.f, q = 0.f;
#pragma unroll
      for (int t = 0; t < 16; t++) { s += psum[t * 64 + tid]; q += psq[t * 64 + tid]; }
      int gcol = n0 + tid;
      if (gcol < N) {
        atomicAdd(&bnsums[gcol], (double)s);
        atomicAdd(&bnsums[72 + gcol], (double)q);
      }
    }
  }
}

// ---------------- fused PNA aggregation ----------------
__global__ void agg_fused_k(const float* __restrict__ XdXs, int ldx, const float* __restrict__ ea,
                            const int* __restrict__ srcI, const int* __restrict__ rp,
                            const int* __restrict__ eids, const float* __restrict__ Wec,
                            const float* __restrict__ bec, float* __restrict__ agg, int F) {
  const int C = 4 * F;
  long long idx = (long long)blockIdx.x * blockDim.x + threadIdx.x;
  if (idx >= (long long)N_NODES * C) return;
  int n = (int)(idx / C), c = (int)(idx % C);
  int s = rp[n], e = rp[n + 1];
  float w0 = Wec[c], w1 = Wec[C + c], w2 = Wec[2 * C + c], bc = bec[c];
  float sum = 0.f, sq = 0.f, mn = INFINITY, mx = -INFINITY;
  for (int i = s; i < e; i++) {
    int eid = eids[i];
    int sr = srcI[eid];
    float v = XdXs[(long long)sr * ldx + C + c] + ea[eid * 3 + 0] * w0 +
              ea[eid * 3 + 1] * w1 + ea[eid * 3 + 2] * w2 + bc;
    sum += v; sq += v * v;
    mn = fminf(mn, v); mx = fmaxf(mx, v);
  }
  int t = c / F, f = c % F;
  long long base = (long long)n * 4 * C + (long long)t * 4 * F;
  float mean, stdv;
  if (e == s) {
    mean = 0.f; mn = 0.f; mx = 0.f; stdv = sqrtf(1e-5f);
  } else {
    float inv = 1.f / (float)(e - s);
    float xd = XdXs[(long long)n * ldx + c];
    float mu = sum * inv;
    float var = sq * inv - mu * mu;
    if (var < 0.f) var = 0.f;
    stdv = sqrtf(var + 1e-5f);
    mean = xd + mu; mn += xd; mx += xd;
  }
  agg[base + f] = mean;
  agg[base + F + f] = mn;
  agg[base + 2 * F + f] = mx;
  agg[base + 3 * F + f] = stdv;
}

// ---------------- weight repacks ----------------
// Bm [F][Nfull]: cols<4F: Wd; <8F: Ws; >=8F: W0 (x-part of post). bfull: 0 | pob.
// Wc [4][4F][64]: cols<54 from pow rows {F+j,5F+j,9F+j}; pad 0
// Wec [3][4F] = ew @ We_sub; bec [4F] = eb @ We_sub + prb
__global__ void repack2_k(const float* __restrict__ prw, const float* __restrict__ pw,
                          const float* __restrict__ ew, const float* __restrict__ eb,
                          const float* __restrict__ prb, const float* __restrict__ pob,
                          float* __restrict__ Bm, float* __restrict__ bfull,
                          float* __restrict__ Wc, float* __restrict__ Wec,
                          float* __restrict__ bec, int F) {
  const int C = 4 * F, F3 = 3 * F, F8 = 8 * F;
  const int Nfull = F8 + 72;
  const int nBm = F * Nfull, nbf = Nfull, nWc = 4 * C * 64, nWec = 3 * C, nbec = C;
  int idx = blockIdx.x * blockDim.x + threadIdx.x;
  if (idx < nBm) {
    int f = idx / Nfull, c = idx % Nfull;
    float v;
    if (c < F8) {
      int cc = (c < C) ? c : (c - C);
      int t = cc / F, o = cc % F;
      int row = (c < C) ? f : (F + f);
      v = prw[((long long)t * F3 + row) * F + o];
    } else {
      int c2 = c - F8;
      int t = c2 / 18, o = c2 % 18;
      v = pw[((long long)t * 13 * F + f) * 18 + o];
    }
    Bm[idx] = v;
  } else if (idx < nBm + nbf) {
    int c = idx - nBm;
    bfull[c] = (c < F8) ? 0.f : pob[c - F8];
  } else if (idx < nBm + nbf + nWc) {
    int j2 = idx - nBm - nbf;
    int t = j2 / (C * 64);
    int rem = j2 % (C * 64);
    int j = rem / 64, col = rem % 64;
    float v = 0.f;
    if (col < 54) {
      int seg = col / 18, o = col % 18;
      int row = (seg == 0) ? (F + j) : ((seg == 1) ? (5 * F + j) : (9 * F + j));
      v = pw[((long long)t * 13 * F + row) * 18 + o];
    }
    Wc[j2] = v;
  } else if (idx < nBm + nbf + nWc + nWec) {
    int j2 = idx - nBm - nbf - nWc;
    int r = j2 / C, c = j2 % C;
    int t = c / F, o = c % F;
    float s = 0.f;
    for (int f = 0; f < F; f++) s += ew[r * F + f] * prw[((long long)t * F3 + 2 * F + f) * F + o];
    Wec[j2] = s;
  } else if (idx < nBm + nbf + nWc + nWec + nbec) {
    int c = idx - (nBm + nbf + nWc + nWec);
    int t = c / F, o = c % F;
    float s = prb[t * F + o];
    for (int f = 0; f < F; f++) s += eb[f] * prw[((long long)t * F3 + 2 * F + f) * F + o];
    bec[c] = s;
  }
}

// ---------------- BN finalize (scale/shift per channel) ----------------
__global__ void bnfinal_k(const double* __restrict__ sums, const float* __restrict__ g,
                          const float* __restrict__ be, float* __restrict__ vsc,
                          float* __restrict__ vsh) {
  int c = threadIdx.x;
  if (c >= 72) return;
  double mu = sums[c] / (double)N_NODES;
  double var = sums[72 + c] / (double)N_NODES - mu * mu;
  if (var < 0.0) var = 0.0;
  float sc = g[c] / sqrtf((float)var + 1e-5f);
  vsc[c] = sc;
  vsh[c] = be[c] - (float)mu * sc;
}

// ---------------- pooling: one block per graph, BN+relu applied ----------------
__global__ __launch_bounds__(256) void pool2_k(const float* __restrict__ y,
                                               const float* __restrict__ vsc,
                                               const float* __restrict__ vsh,
                                               const int* __restrict__ grp,
                                               float* __restrict__ gpT) {
  int g = blockIdx.x;
  int s = grp[g], e = grp[g + 1];
  __shared__ float acc[72];
  if (threadIdx.x < 72) acc[threadIdx.x] = 0.f;
  __syncthreads();
  int tot = (e - s) * 72;
  for (int idx = threadIdx.x; idx < tot; idx += 256) {
    int n = s + idx / 72, c = idx % 72;
    float v = y[(long long)n * 72 + c] * vsc[c] + vsh[c];
    if (v > 0.f) atomicAdd(&acc[c], v);
  }
  __syncthreads();
  if (threadIdx.x < 72) gpT[threadIdx.x * N_GRAPHS + g] = acc[threadIdx.x];
}

// ---------------- MLP heads, column-parallel ----------------
struct HeadP {
  const float *w1, *b1, *g1, *be1, *w2, *b2, *g2, *be2, *w3, *b3;
};

__device__ inline float wred(float v) {
#pragma unroll
  for (int off = 32; off > 0; off >>= 1) v += __shfl_xor(v, off);
  return v;
}

__global__ __launch_bounds__(512) void head_l1_k(const float* __restrict__ gpT, HeadP hA,
                                                 HeadP hB, HeadP hC, float* __restrict__ h1T) {
  int head = blockIdx.x / 50, o = blockIdx.x % 50;
  HeadP hp = (head == 0) ? hA : ((head == 1) ? hB : hC);
  int r = threadIdx.x, lane = r & 63, wave = r >> 6;
  __shared__ float rs[8], rq[8], sc_sh, sh_sh;
  float acc = hp.b1[o];
  for (int k = 0; k < 72; k++) acc += gpT[k * N_GRAPHS + r] * hp.w1[k * 50 + o];
  float s = wred(acc), q = wred(acc * acc);
  if (lane == 0) { rs[wave] = s; rq[wave] = q; }
  __syncthreads();
  if (r == 0) {
    float ts = 0.f, tq = 0.f;
#pragma unroll
    for (int i = 0; i < 8; i++) { ts += rs[i]; tq += rq[i]; }
    float mu = ts / (float)N_GRAPHS;
    float var = tq / (float)N_GRAPHS - mu * mu;
    if (var < 0.f) var = 0.f;
    float sc = hp.g1[o] / sqrtf(var + 1e-5f);
    sc_sh = sc; sh_sh = hp.be1[o] - mu * sc;
  }
  __syncthreads();
  float v = acc * sc_sh + sh_sh;
  h1T[(head * 50 + o) * N_GRAPHS + r] = v > 0.f ? v : 0.f;
}

__global__ __launch_bounds__(512) void head_l2_k(const float* __restrict__ h1T, HeadP hA,
                                                 HeadP hB, HeadP hC, float* __restrict__ h2T) {
  int head = blockIdx.x / 25, o = blockIdx.x % 25;
  HeadP hp = (head == 0) ? hA : ((head == 1) ? hB : hC);
  int r = threadIdx.x, lane = r & 63, wave = r >> 6;
  __shared__ float rs[8], rq[8], sc_sh, sh_sh;
  float acc = hp.b2[o];
  const float* hb = h1T + head * 50 * N_GRAPHS;
  for (int k = 0; k < 50; k++) acc += hb[k * N_GRAPHS + r] * hp.w2[k * 25 + o];
  float s = wred(acc), q = wred(acc * acc);
  if (lane == 0) { rs[wave] = s; rq[wave] = q; }
  __syncthreads();
  if (r == 0) {
    float ts = 0.f, tq = 0.f;
#pragma unroll
    for (int i = 0; i < 8; i++) { ts += rs[i]; tq += rq[i]; }
    float mu = ts / (float)N_GRAPHS;
    float var = tq / (float)N_GRAPHS - mu * mu;
    if (var < 0.f) var = 0.f;
    float sc = hp.g2[o] / sqrtf(var + 1e-5f);
    sc_sh = sc; sh_sh = hp.be2[o] - mu * sc;
  }
  __syncthreads();
  float v = acc * sc_sh + sh_sh;
  h2T[(head * 25 + o) * N_GRAPHS + r] = v > 0.f ? v : 0.f;
}

__global__ __launch_bounds__(512) void head_l3_k(const float* __restrict__ h2T, HeadP hA,
                                                 HeadP hB, HeadP hC, float* __restrict__ out) {
  int head = blockIdx.x;
  HeadP hp = (head == 0) ? hA : ((head == 1) ? hB : hC);
  int r = threadIdx.x;
  int od = (head == 0) ? 3 : 7;
  float acc3[7];
#pragma unroll
  for (int o = 0; o < 7; o++) acc3[o] = (o < od) ? hp.b3[o] : 0.f;
  const float* hb = h2T + head * 25 * N_GRAPHS;
  for (int k = 0; k < 25; k++) {
    float hv = hb[k * N_GRAPHS + r];
#pragma unroll
    for (int o = 0; o < 7; o++)
      if (o < od) acc3[o] += hv * hp.w3[k * od + o];
  }
  float* og = out + r * 20;  // [512][2][10]
  if (head == 0) {
#pragma unroll
    for (int j = 0; j < 3; j++) {
      float v = tanhf(acc3[j]);
      og[7 + j] = v;
      og[17 + j] = v;
    }
  } else {
    const float unit[7] = {1.f, 1.f, 100.f, 0.01f, 1000.f, 0.f, 1e-5f};
    int base = (head == 1) ? 0 : 10;
#pragma unroll
    for (int j = 0; j < 7; j++) {
      float v = acc3[j];
      v = v > 0.f ? v : 0.f;
      og[base + j] = v + unit[j];
    }
  }
}

// ---------------- host launch ----------------
static inline char* alignp(char* p, size_t a) {
  return (char*)(((uintptr_t)p + (a - 1)) & ~(uintptr_t)(a - 1));
}

extern "C" void kernel_launch(void* const* d_in, const int* in_sizes, int n_in, void* d_out,
                              int out_size, void* d_ws, size_t ws_size, hipStream_t stream) {
  const float* x = (const float*)d_in[0];
  const float* edge_attr = (const float*)d_in[1];
  const int* srcp = (const int*)d_in[2];
  const int* dstp = srcp + N_EDGES;
  const int* batch = (const int*)d_in[3];

  const float *EWv[4], *EBv[4], *PRW[4], *PRB[4], *PW[4], *POB[4], *LWv[4], *LBv[4], *Gv[4],
      *BEv[4];
  EWv[0] = (const float*)d_in[4];  EBv[0] = (const float*)d_in[5];
  PRW[0] = (const float*)d_in[6];  PRB[0] = (const float*)d_in[7];
  PW[0] = (const float*)d_in[8];   POB[0] = (const float*)d_in[9];
  LWv[0] = (const float*)d_in[10]; LBv[0] = (const float*)d_in[11];
  Gv[0] = (const float*)d_in[12];  BEv[0] = (const float*)d_in[13];
  const float* cs_ew = (const float*)d_in[14];
  const float* cs_eb = (const float*)d_in[15];
  const float* cs_prw = (const float*)d_in[16];
  const float* cs_prb = (const float*)d_in[17];
  const float* cs_pow = (const float*)d_in[18];
  const float* cs_pob = (const float*)d_in[19];
  const float* cs_lw = (const float*)d_in[20];
  const float* cs_lb = (const float*)d_in[21];
  const float* cs_g = (const float*)d_in[22];
  const float* cs_be = (const float*)d_in[23];
  for (int i = 1; i < 4; i++) {
    int j = i - 1;
    EWv[i] = cs_ew + j * 3 * 72;        EBv[i] = cs_eb + j * 72;
    PRW[i] = cs_prw + j * 4 * 216 * 72; PRB[i] = cs_prb + j * 4 * 72;
    PW[i] = cs_pow + j * 4 * 936 * 18;  POB[i] = cs_pob + j * 4 * 18;
    LWv[i] = cs_lw + j * 72 * 72;       LBv[i] = cs_lb + j * 72;
    Gv[i] = cs_g + j * 72;              BEv[i] = cs_be + j * 72;
  }
  HeadP heads[3];
  for (int m = 0; m < 3; m++) {
    const float** pp = (const float**)&heads[m];
    for (int k = 0; k < 10; k++) pp[k] = (const float*)d_in[24 + m * 10 + k];
  }

  // workspace carve
  char* p = (char*)d_ws;
  int* deg_i = (int*)p;   p += N_NODES * 4;
  int* cursor = (int*)p;  p += N_NODES * 4;
  int* row_ptr = (int*)p; p += (N_NODES + 1) * 4;
  int* eids = (int*)p;    p += N_EDGES * 4;
  int* grp = (int*)p;     p += (N_GRAPHS + 1) * 4;
  p = alignp(p, 256);
  float* amp = (float*)p; p += N_NODES * 4;
  p = alignp(p, 256);
  float* R = (float*)p;   p += (size_t)N_NODES * 648 * 4;  // XdXs | y0 (cols 8F..8F+71)
  p = alignp(p, 256);
  float* y1 = (float*)p;  p += (size_t)N_NODES * 72 * 4;
  p = alignp(p, 256);
  float* agg = (float*)p; p += (size_t)N_NODES * 1152 * 4;
  p = alignp(p, 256);
  float* Bm = (float*)p;    p += 72 * 648 * 4;
  float* bfull = (float*)p; p += 648 * 4;
  float* Wc = (float*)p;    p += 4 * 288 * 64 * 4;
  float* Wec = (float*)p;   p += 3 * 288 * 4;
  float* bec = (float*)p;   p += 288 * 4;
  float* vsc = (float*)p;   p += 72 * 4;
  float* vsh = (float*)p;   p += 72 * 4;
  p = alignp(p, 256);
  double* bnsums = (double*)p; p += 144 * 8;
  p = alignp(p, 256);
  float* gpT = (float*)p;  p += 72 * N_GRAPHS * 4;
  float* h1T = (float*)p;  p += 3 * 50 * N_GRAPHS * 4;
  float* h2T = (float*)p;  p += 3 * 25 * N_GRAPHS * 4;
  (void)ws_size; (void)n_in; (void)in_sizes; (void)out_size;

  static const double hist[7] = {67167, 3157428, 5106064, 885236, 453935, 0, 11152};
  double num = 0, den = 0;
  for (int i = 0; i < 7; i++) { num += log((double)(i + 1)) * hist[i]; den += hist[i]; }
  float adl = (float)(num / den);

  // CSR + amp + graph boundaries
  hipMemsetAsync(deg_i, 0, 2 * N_NODES * 4, stream);
  count_deg_k<<<(N_EDGES + 255) / 256, 256, 0, stream>>>(dstp, deg_i);
  scan_rowptr_k<<<1, 1024, 0, stream>>>(deg_i, row_ptr);
  fill_csr_k<<<(N_EDGES + 255) / 256, 256, 0, stream>>>(dstp, row_ptr, cursor, eids);
  amp_k<<<(N_NODES + 255) / 256, 256, 0, stream>>>(deg_i, amp, adl);
  gboundary_k<<<(N_NODES + 255) / 256, 256, 0, stream>>>(batch, grp);

  const int gM = (N_NODES + 127) / 128;  // 157
  for (int l = 0; l < 4; l++) {
    const int F = (l == 0) ? 9 : 72;
    const int C = 4 * F, Nfull = 8 * F + 72;
    float* y0l = R + 8 * F;  // y0 columns live at col offset 8F of the merged output

    int nrep = F * Nfull + Nfull + 4 * C * 64 + 3 * C + C;
    repack2_k<<<(nrep + 255) / 256, 256, 0, stream>>>(PRW[l], PW[l], EWv[l], EBv[l], PRB[l],
                                                      POB[l], Bm, bfull, Wc, Wec, bec, F);
    hipMemsetAsync(bnsums, 0, 144 * 8, stream);

    // merged GEMM: R[:, :Nfull] = act(prev) @ [Wd|Ws|W0] + [0|0|pob]
    {
      dim3 g(gM, (Nfull + 63) / 64, 1);
      if (l == 0)
        sgemm2_k<0, 0, 0><<<g, 256, 0, stream>>>(x, Bm, R, bfull, N_NODES, Nfull, F, F, Nfull,
                                                 Nfull, Nfull, Nfull, 0, 0, nullptr, nullptr,
                                                 nullptr, nullptr, 0, nullptr);
      else
        sgemm2_k<1, 1, 0><<<g, 256, 0, stream>>>(y1, Bm, R, bfull, N_NODES, Nfull, F, 72, Nfull,
                                                 Nfull, Nfull, Nfull, 0, 0, vsc, vsh, nullptr,
                                                 nullptr, 0, nullptr);
    }

    // fused aggregation -> agg [N][16F]
    {
      long long tot = (long long)N_NODES * C;
      agg_fused_k<<<(int)((tot + 255) / 256), 256, 0, stream>>>(R, Nfull, edge_attr, srcp,
                                                                row_ptr, eids, Wec, bec, agg, F);
    }

    // P-GEMM with combine epilogue: y0 += combine(agg_t @ Wc_t, amp)
    {
      dim3 g(gM, 1, 4);
      sgemm2_k<1, 0, 1><<<g, 256, 0, stream>>>(agg, Wc, nullptr, nullptr, N_NODES, 54, C, 4 * C,
                                               64, 0, 64, 56, C, (long long)C * 64, nullptr,
                                               nullptr, amp, y0l, Nfull, nullptr);
    }

    // y1 = y0 @ lw + lb, with BN-stats epilogue
    {
      dim3 g(gM, 2, 1);
      sgemm2_k<1, 0, 2><<<g, 256, 0, stream>>>(y0l, LWv[l], y1, LBv[l], N_NODES, 72, 72, Nfull,
                                               72, 72, 72, 72, 0, 0, nullptr, nullptr, nullptr,
                                               nullptr, 0, bnsums);
    }

    bnfinal_k<<<1, 128, 0, stream>>>(bnsums, Gv[l], BEv[l], vsc, vsh);
  }

  // pool with final BN+relu applied -> gpT [72][512]
  pool2_k<<<N_GRAPHS, 256, 0, stream>>>(y1, vsc, vsh, grp, gpT);

  head_l1_k<<<150, 512, 0, stream>>>(gpT, heads[0], heads[1], heads[2], h1T);
  head_l2_k<<<75, 512, 0, stream>>>(h1T, heads[0], heads[1], heads[2], h2T);
  head_l3_k<<<3, 512, 0, stream>>>(h2T, heads[0], heads[1], heads[2], (float*)d_out);
}

// Round 8
// 882.774 us; speedup vs baseline: 2.1865x; 1.0659x over previous
//
#include <hip/hip_runtime.h>
#include <hip/hip_bf16.h>
#include <math.h>
#include <cstdint>

#define N_NODES 20000
#define N_EDGES 60000
#define N_GRAPHS 512
#define NT 4

typedef __attribute__((ext_vector_type(8))) short bf8v;
typedef __attribute__((ext_vector_type(4))) float f4v;

// ---------------- bf16 split helpers (pure bit ops) ----------------
__device__ inline unsigned short bf_rn(float a) {
  unsigned int x = __float_as_uint(a);
  unsigned int lsb = (x >> 16) & 1u;
  x += 0x7fffu + lsb;  // round-to-nearest-even
  return (unsigned short)(x >> 16);
}
__device__ inline void bsplit(float a, unsigned short& h, unsigned short& l) {
  unsigned short hu = bf_rn(a);
  float hf = __uint_as_float(((unsigned int)hu) << 16);
  h = hu;
  l = bf_rn(a - hf);
}

// ---------------- CSR build ----------------
__global__ void count_deg_k(const int* __restrict__ dst, int* __restrict__ deg) {
  int e = blockIdx.x * blockDim.x + threadIdx.x;
  if (e < N_EDGES) atomicAdd(&deg[dst[e]], 1);
}

__global__ void scan_rowptr_k(const int* __restrict__ deg, int* __restrict__ rp) {
  __shared__ int ss[1024];
  int tid = threadIdx.x;
  const int per = (N_NODES + 1023) / 1024;  // 20
  int base = tid * per;
  int s = 0;
  for (int i = 0; i < per; i++) { int idx = base + i; if (idx < N_NODES) s += deg[idx]; }
  ss[tid] = s;
  __syncthreads();
  for (int off = 1; off < 1024; off <<= 1) {
    int v = (tid >= off) ? ss[tid - off] : 0;
    __syncthreads();
    ss[tid] += v;
    __syncthreads();
  }
  int run = ss[tid] - s;  // exclusive prefix
  for (int i = 0; i < per; i++) {
    int idx = base + i;
    if (idx < N_NODES) { rp[idx] = run; run += deg[idx]; }
  }
  if (tid == 0) rp[N_NODES] = ss[1023];
}

__global__ void fill_csr_k(const int* __restrict__ dst, const int* __restrict__ rp,
                           int* __restrict__ cur, int* __restrict__ eids) {
  int e = blockIdx.x * blockDim.x + threadIdx.x;
  if (e < N_EDGES) {
    int d = dst[e];
    int pos = atomicAdd(&cur[d], 1);
    eids[rp[d] + pos] = e;
  }
}

__global__ void amp_k(const int* __restrict__ deg, float* __restrict__ amp, float adl) {
  int n = blockIdx.x * blockDim.x + threadIdx.x;
  if (n < N_NODES) {
    float d = (float)(deg[n] > 0 ? deg[n] : 1);
    amp[n] = logf(d + 1.0f) / adl;
  }
}

__global__ void gboundary_k(const int* __restrict__ batch, int* __restrict__ grp) {
  int n = blockIdx.x * blockDim.x + threadIdx.x;
  if (n >= N_NODES) return;
  int bn = batch[n];
  int bp = (n == 0) ? -1 : batch[n - 1];
  for (int g = bp + 1; g <= bn; g++) grp[g] = n;
  if (n == N_NODES - 1)
    for (int g = bn + 1; g <= N_GRAPHS; g++) grp[g] = N_NODES;
}

// ---------------- conversion kernels ----------------
// x [20000][9] f32 -> hi/lo [20000][32] bf16 zero-padded
__global__ void cvt_x_k(const float* __restrict__ x, unsigned short* __restrict__ xh,
                        unsigned short* __restrict__ xl) {
  int idx = blockIdx.x * blockDim.x + threadIdx.x;
  if (idx >= N_NODES * 32) return;
  int n = idx >> 5, k = idx & 31;
  float a = (k < 9) ? x[n * 9 + k] : 0.f;
  bsplit(a, xh[idx], xl[idx]);
}

// act = relu(y1*vsc+vsh) -> hi/lo [20000][96] zero-padded (72->96)
__global__ void cvt_act_k(const float* __restrict__ y1, const float* __restrict__ vsc,
                          const float* __restrict__ vsh, unsigned short* __restrict__ ah,
                          unsigned short* __restrict__ al) {
  int idx = blockIdx.x * blockDim.x + threadIdx.x;
  if (idx >= N_NODES * 96) return;
  int n = idx / 96, k = idx - n * 96;
  float a = 0.f;
  if (k < 72) {
    a = y1[n * 72 + k] * vsc[k] + vsh[k];
    if (a < 0.f) a = 0.f;
  }
  bsplit(a, ah[idx], al[idx]);
}

// ---------------- MFMA split-bf16 GEMM: 128x64 tile, 4 waves (2Mx2N) ----------------
// C[M,N] = A[M,Kp] @ B^T[N,Kp] (both pre-split hi/lo bf16, zero-padded in k).
// EPI=0: C store (+bias). EPI=1: PNA-combine epilogue -> y0 += (no C store).
template <int EPI>
__global__ __launch_bounds__(256, 2) void mgemm_k(
    const unsigned short* __restrict__ Ah, const unsigned short* __restrict__ Al,
    const unsigned short* __restrict__ Bh, const unsigned short* __restrict__ Bl,
    float* __restrict__ C, const float* __restrict__ bias, int M, int N, int Kp, int lda,
    int ldb, int ldc, long long bsA, long long bsB, const float* __restrict__ amp,
    float* __restrict__ y0, int ldy) {
  __shared__ __align__(16) unsigned short smem[15360];  // 30720 B
  unsigned short* sAh = smem;           // [128][40]
  unsigned short* sAl = smem + 5120;    // [128][40]
  unsigned short* sBh = smem + 10240;   // [64][40]
  unsigned short* sBl = smem + 12800;   // [64][40]

  const int tid = threadIdx.x;
  const int lane = tid & 63, wid = tid >> 6;
  const int wm = wid >> 1, wn = wid & 1;          // wave grid 2M x 2N
  const int lrow = lane & 15, lko = (lane >> 4) * 8;
  const int m0 = blockIdx.x * 128, n0 = blockIdx.y * 64;
  const int z = blockIdx.z;
  Ah += bsA * z; Al += bsA * z; Bh += bsB * z; Bl += bsB * z;

  f4v acc[4][2];
#pragma unroll
  for (int i = 0; i < 4; i++)
#pragma unroll
    for (int j = 0; j < 2; j++) acc[i][j] = (f4v){0.f, 0.f, 0.f, 0.f};

  const uint4 zero4 = make_uint4(0, 0, 0, 0);
  for (int k0 = 0; k0 < Kp; k0 += 32) {
    // stage A tile 128x32 (hi+lo): 2 chunks of 8 bf16 per thread
#pragma unroll
    for (int it = 0; it < 2; ++it) {
      int u = it * 256 + tid;
      int row = u >> 2, ch = u & 3;
      int gm = m0 + row;
      uint4 vh = zero4, vl = zero4;
      if (gm < M) {
        long long go = (long long)gm * lda + k0 + ch * 8;
        vh = *(const uint4*)&Ah[go];
        vl = *(const uint4*)&Al[go];
      }
      *(uint4*)&sAh[row * 40 + ch * 8] = vh;
      *(uint4*)&sAl[row * 40 + ch * 8] = vl;
    }
    // stage B tile 64x32 (hi+lo): 1 chunk per thread
    {
      int col = tid >> 2, ch = tid & 3;
      int gn = n0 + col;
      uint4 vh = zero4, vl = zero4;
      if (gn < N) {
        long long go = (long long)gn * ldb + k0 + ch * 8;
        vh = *(const uint4*)&Bh[go];
        vl = *(const uint4*)&Bl[go];
      }
      *(uint4*)&sBh[col * 40 + ch * 8] = vh;
      *(uint4*)&sBl[col * 40 + ch * 8] = vl;
    }
    __syncthreads();
    bf8v bhv[2], blv[2];
#pragma unroll
    for (int ni = 0; ni < 2; ++ni) {
      int cb = (wn * 32 + ni * 16 + lrow) * 40 + lko;
      bhv[ni] = *(const bf8v*)&sBh[cb];
      blv[ni] = *(const bf8v*)&sBl[cb];
    }
#pragma unroll
    for (int mi = 0; mi < 4; ++mi) {
      int ab = (wm * 64 + mi * 16 + lrow) * 40 + lko;
      bf8v ahv = *(const bf8v*)&sAh[ab];
      bf8v alv = *(const bf8v*)&sAl[ab];
#pragma unroll
      for (int ni = 0; ni < 2; ++ni) {
        acc[mi][ni] = __builtin_amdgcn_mfma_f32_16x16x32_bf16(ahv, bhv[ni], acc[mi][ni], 0, 0, 0);
        acc[mi][ni] = __builtin_amdgcn_mfma_f32_16x16x32_bf16(ahv, blv[ni], acc[mi][ni], 0, 0, 0);
        acc[mi][ni] = __builtin_amdgcn_mfma_f32_16x16x32_bf16(alv, bhv[ni], acc[mi][ni], 0, 0, 0);
      }
    }
    __syncthreads();
  }

  if (EPI == 1) {
    // stage P tile into LDS (f32, aliases staging buffers), combine into y0
    float* Ps = (float*)smem;  // [128][57] = 29184 B <= 30720
#pragma unroll
    for (int mi = 0; mi < 4; ++mi)
#pragma unroll
      for (int ni = 0; ni < 2; ++ni) {
        int col = wn * 32 + ni * 16 + lrow;
        if (col < 56) {
#pragma unroll
          for (int r = 0; r < 4; ++r) {
            int row = wm * 64 + mi * 16 + ((lane >> 4) << 2) + r;
            Ps[row * 57 + col] = acc[mi][ni][r];
          }
        }
      }
    __syncthreads();
#pragma unroll
    for (int it = 0; it < 9; ++it) {
      int item = it * 256 + tid;
      int r = item / 18, o = item - r * 18;
      int gm = m0 + r;
      if (gm < M) {
        float a = amp[gm];
        float v = Ps[r * 57 + o] + a * Ps[r * 57 + 18 + o] + Ps[r * 57 + 36 + o] / a;
        y0[(long long)gm * ldy + z * 18 + o] += v;
      }
    }
    return;
  }
  // EPI == 0: store with bias. D layout: row=(lane>>4)*4+r, col=lane&15 per tile.
#pragma unroll
  for (int ni = 0; ni < 2; ++ni) {
    int col = n0 + wn * 32 + ni * 16 + lrow;
    if (col >= N) continue;
    float bv = bias ? bias[col] : 0.f;
#pragma unroll
    for (int mi = 0; mi < 4; ++mi) {
#pragma unroll
      for (int r = 0; r < 4; ++r) {
        int row = m0 + wm * 64 + mi * 16 + ((lane >> 4) << 2) + r;
        if (row < M) C[(long long)row * ldc + col] = acc[mi][ni][r] + bv;
      }
    }
  }
}

// ---------------- fp32 SGEMM (kept for y1-GEMM with BN-stats epilogue) ----------------
template <int AVEC, int BNA, int EPI>
__global__ __launch_bounds__(256, 2) void sgemm2_k(
    const float* __restrict__ A, const float* __restrict__ B, float* __restrict__ C,
    const float* __restrict__ bias, int M, int N, int K, int lda, int ldb, int ldc,
    int nb, int ns, long long bsA, long long bsB,
    const float* __restrict__ vsc, const float* __restrict__ vsh,
    const float* __restrict__ amp, float* __restrict__ y0, int ldy,
    double* __restrict__ bnsums) {
  constexpr int SM = (EPI == 1) ? 128 * 57 : (16 * 128 + 16 * 64);
  __shared__ float smem[SM];
  float(*As)[128] = (float(*)[128])smem;
  float(*Bs)[64] = (float(*)[64])(smem + 16 * 128);

  const int tid = threadIdx.x;
  const int tx = tid & 15, ty = tid >> 4;
  const int m0 = blockIdx.x * 128, n0 = blockIdx.y * 64;
  const int z = blockIdx.z;
  A += bsA * z; B += bsB * z;

  float acc[8][4] = {};
  for (int k0 = 0; k0 < K; k0 += 16) {
    if (AVEC) {
#pragma unroll
      for (int it = 0; it < 2; ++it) {
        int u = it * 256 + tid;
        int row = u >> 2, q = u & 3;
        int gm = m0 + row, gk = k0 + 4 * q;
        float4 v = make_float4(0.f, 0.f, 0.f, 0.f);
        if (gm < M && gk < K) {
          v = *(const float4*)&A[(long long)gm * lda + gk];
          if (BNA) {
            float4 sc = *(const float4*)&vsc[gk];
            float4 sh = *(const float4*)&vsh[gk];
            v.x = fmaxf(v.x * sc.x + sh.x, 0.f);
            v.y = fmaxf(v.y * sc.y + sh.y, 0.f);
            v.z = fmaxf(v.z * sc.z + sh.z, 0.f);
            v.w = fmaxf(v.w * sc.w + sh.w, 0.f);
          }
        }
        As[4 * q + 0][row] = v.x;
        As[4 * q + 1][row] = v.y;
        As[4 * q + 2][row] = v.z;
        As[4 * q + 3][row] = v.w;
      }
    } else {
#pragma unroll
      for (int it = 0; it < 8; ++it) {
        int u = it * 256 + tid;
        int row = u >> 4, kk = u & 15;
        int gm = m0 + row, gk = k0 + kk;
        float v = 0.f;
        if (gm < M && gk < K) {
          v = A[(long long)gm * lda + gk];
          if (BNA) v = fmaxf(v * vsc[gk] + vsh[gk], 0.f);
        }
        As[kk][row] = v;
      }
    }
    {
      int kk = tid >> 4, n4 = (tid & 15) * 4;
      int gk = k0 + kk, gn = n0 + n4;
      float4 v = make_float4(0.f, 0.f, 0.f, 0.f);
      if (gk < K && gn < nb) v = *(const float4*)&B[(long long)gk * ldb + gn];
      *(float4*)&Bs[kk][n4] = v;
    }
    __syncthreads();
#pragma unroll
    for (int kk = 0; kk < 16; ++kk) {
      float a[8], b[4];
#pragma unroll
      for (int i = 0; i < 8; i++) a[i] = As[kk][ty * 8 + i];
#pragma unroll
      for (int j = 0; j < 4; j++) b[j] = Bs[kk][tx * 4 + j];
#pragma unroll
      for (int i = 0; i < 8; i++)
#pragma unroll
        for (int j = 0; j < 4; j++) acc[i][j] += a[i] * b[j];
    }
    __syncthreads();
  }

  if (EPI == 1) {
    float(*Ps)[57] = (float(*)[57])smem;
    int c0 = tx * 4;
#pragma unroll
    for (int i = 0; i < 8; i++) {
      if (c0 < 56) {
#pragma unroll
        for (int j = 0; j < 4; j++) Ps[ty * 8 + i][c0 + j] = acc[i][j];
      }
    }
    __syncthreads();
#pragma unroll
    for (int it = 0; it < 9; ++it) {
      int item = it * 256 + tid;
      int r = item / 18, o = item - r * 18;
      int gm = m0 + r;
      if (gm < M) {
        float a = amp[gm];
        float v = Ps[r][o] + a * Ps[r][18 + o] + Ps[r][36 + o] / a;
        y0[(long long)gm * ldy + z * 18 + o] += v;
      }
    }
    return;
  }

  int gn = n0 + tx * 4;
  float cs[4] = {0.f, 0.f, 0.f, 0.f}, cq[4] = {0.f, 0.f, 0.f, 0.f};
  if (gn < ns) {
    float b0 = 0.f, b1 = 0.f, b2 = 0.f, b3 = 0.f;
    if (bias) { b0 = bias[gn]; b1 = bias[gn + 1]; b2 = bias[gn + 2]; b3 = bias[gn + 3]; }
#pragma unroll
    for (int i = 0; i < 8; i++) {
      int gm = m0 + ty * 8 + i;
      if (gm >= M) continue;
      float4 v;
      v.x = acc[i][0] + b0; v.y = acc[i][1] + b1;
      v.z = acc[i][2] + b2; v.w = acc[i][3] + b3;
      *(float4*)&C[(long long)gm * ldc + gn] = v;
      if (EPI == 2) {
        cs[0] += v.x; cs[1] += v.y; cs[2] += v.z; cs[3] += v.w;
        cq[0] += v.x * v.x; cq[1] += v.y * v.y; cq[2] += v.z * v.z; cq[3] += v.w * v.w;
      }
    }
  }
  if (EPI == 2) {
    __syncthreads();
    float* psum = smem;
    float* psq = smem + 1024;
#pragma unroll
    for (int j = 0; j < 4; j++) {
      psum[ty * 64 + tx * 4 + j] = cs[j];
      psq[ty * 64 + tx * 4 + j] = cq[j];
    }
    __syncthreads();
    if (tid < 64) {
      float s = 0.f, q = 0.f;
#pragma unroll
      for (int t = 0; t < 16; t++) { s += psum[t * 64 + tid]; q += psq[t * 64 + tid]; }
      int gcol = n0 + tid;
      if (gcol < N) {
        atomicAdd(&bnsums[gcol], (double)s);
        atomicAdd(&bnsums[72 + gcol], (double)q);
      }
    }
  }
}

// ---------------- fused PNA aggregation -> bf16 hi/lo split output ----------------
__global__ void agg_fused_k(const float* __restrict__ XdXs, int ldx, const float* __restrict__ ea,
                            const int* __restrict__ srcI, const int* __restrict__ rp,
                            const int* __restrict__ eids, const float* __restrict__ Wec,
                            const float* __restrict__ bec, unsigned short* __restrict__ aggh,
                            unsigned short* __restrict__ aggl, int F, int Kpz) {
  const int C = 4 * F;
  long long idx = (long long)blockIdx.x * blockDim.x + threadIdx.x;
  if (idx >= (long long)N_NODES * C) return;
  int n = (int)(idx / C), c = (int)(idx % C);
  int s = rp[n], e = rp[n + 1];
  float w0 = Wec[c], w1 = Wec[C + c], w2 = Wec[2 * C + c], bc = bec[c];
  float sum = 0.f, sq = 0.f, mn = INFINITY, mx = -INFINITY;
  for (int i = s; i < e; i++) {
    int eid = eids[i];
    int sr = srcI[eid];
    float v = XdXs[(long long)sr * ldx + C + c] + ea[eid * 3 + 0] * w0 +
              ea[eid * 3 + 1] * w1 + ea[eid * 3 + 2] * w2 + bc;
    sum += v; sq += v * v;
    mn = fminf(mn, v); mx = fmaxf(mx, v);
  }
  int t = c / F, f = c % F;
  float mean, stdv;
  if (e == s) {
    mean = 0.f; mn = 0.f; mx = 0.f; stdv = sqrtf(1e-5f);
  } else {
    float inv = 1.f / (float)(e - s);
    float xd = XdXs[(long long)n * ldx + c];
    float mu = sum * inv;
    float var = sq * inv - mu * mu;
    if (var < 0.f) var = 0.f;
    stdv = sqrtf(var + 1e-5f);
    mean = xd + mu; mn += xd; mx += xd;
  }
  long long base = (long long)n * 4 * Kpz + (long long)t * Kpz;
  bsplit(mean, aggh[base + f], aggl[base + f]);
  bsplit(mn, aggh[base + F + f], aggl[base + F + f]);
  bsplit(mx, aggh[base + 2 * F + f], aggl[base + 2 * F + f]);
  bsplit(stdv, aggh[base + 3 * F + f], aggl[base + 3 * F + f]);
}

// ---------------- weight repack: pre-transposed, pre-split bf16 ----------------
// BmT [Nfull][KpA] (k zero-pad F->KpA); bfull [Nfull]; WcT [4][64][KpW] (zero-pad);
// Wec [3][C] f32; bec [C] f32.
__global__ void repack3_k(const float* __restrict__ prw, const float* __restrict__ pw,
                          const float* __restrict__ ew, const float* __restrict__ eb,
                          const float* __restrict__ prb, const float* __restrict__ pob,
                          unsigned short* __restrict__ BmTh, unsigned short* __restrict__ BmTl,
                          float* __restrict__ bfull, unsigned short* __restrict__ WcTh,
                          unsigned short* __restrict__ WcTl, float* __restrict__ Wec,
                          float* __restrict__ bec, int F, int KpA, int KpW) {
  const int C = 4 * F, F3 = 3 * F, F8 = 8 * F;
  const int Nfull = F8 + 72;
  const int nBmT = Nfull * KpA, nbf = Nfull, nWcT = 4 * 64 * KpW, nWec = 3 * C, nbec = C;
  int idx = blockIdx.x * blockDim.x + threadIdx.x;
  if (idx < nBmT) {
    int c = idx / KpA, k = idx % KpA;
    float v = 0.f;
    if (k < F) {
      int f = k;
      if (c < F8) {
        int cc = (c < C) ? c : (c - C);
        int t = cc / F, o = cc % F;
        int row = (c < C) ? f : (F + f);
        v = prw[((long long)t * F3 + row) * F + o];
      } else {
        int c2 = c - F8;
        int t = c2 / 18, o = c2 % 18;
        v = pw[((long long)t * 13 * F + f) * 18 + o];
      }
    }
    bsplit(v, BmTh[idx], BmTl[idx]);
  } else if (idx < nBmT + nbf) {
    int c = idx - nBmT;
    bfull[c] = (c < F8) ? 0.f : pob[c - F8];
  } else if (idx < nBmT + nbf + nWcT) {
    int j = idx - nBmT - nbf;
    int t = j / (64 * KpW);
    int rem = j % (64 * KpW);
    int col = rem / KpW, k = rem % KpW;
    float v = 0.f;
    if (col < 54 && k < C) {
      int seg = col / 18, o = col % 18;
      int row = (seg == 0) ? (F + k) : ((seg == 1) ? (5 * F + k) : (9 * F + k));
      v = pw[((long long)t * 13 * F + row) * 18 + o];
    }
    bsplit(v, WcTh[j], WcTl[j]);
  } else if (idx < nBmT + nbf + nWcT + nWec) {
    int j2 = idx - nBmT - nbf - nWcT;
    int r = j2 / C, c = j2 % C;
    int t = c / F, o = c % F;
    float s = 0.f;
    for (int f = 0; f < F; f++) s += ew[r * F + f] * prw[((long long)t * F3 + 2 * F + f) * F + o];
    Wec[j2] = s;
  } else if (idx < nBmT + nbf + nWcT + nWec + nbec) {
    int c = idx - (nBmT + nbf + nWcT + nWec);
    int t = c / F, o = c % F;
    float s = prb[t * F + o];
    for (int f = 0; f < F; f++) s += eb[f] * prw[((long long)t * F3 + 2 * F + f) * F + o];
    bec[c] = s;
  }
}

// ---------------- BN finalize ----------------
__global__ void bnfinal_k(const double* __restrict__ sums, const float* __restrict__ g,
                          const float* __restrict__ be, float* __restrict__ vsc,
                          float* __restrict__ vsh) {
  int c = threadIdx.x;
  if (c >= 72) return;
  double mu = sums[c] / (double)N_NODES;
  double var = sums[72 + c] / (double)N_NODES - mu * mu;
  if (var < 0.0) var = 0.0;
  float sc = g[c] / sqrtf((float)var + 1e-5f);
  vsc[c] = sc;
  vsh[c] = be[c] - (float)mu * sc;
}

// ---------------- pooling ----------------
__global__ __launch_bounds__(256) void pool2_k(const float* __restrict__ y,
                                               const float* __restrict__ vsc,
                                               const float* __restrict__ vsh,
                                               const int* __restrict__ grp,
                                               float* __restrict__ gpT) {
  int g = blockIdx.x;
  int s = grp[g], e = grp[g + 1];
  __shared__ float acc[72];
  if (threadIdx.x < 72) acc[threadIdx.x] = 0.f;
  __syncthreads();
  int tot = (e - s) * 72;
  for (int idx = threadIdx.x; idx < tot; idx += 256) {
    int n = s + idx / 72, c = idx % 72;
    float v = y[(long long)n * 72 + c] * vsc[c] + vsh[c];
    if (v > 0.f) atomicAdd(&acc[c], v);
  }
  __syncthreads();
  if (threadIdx.x < 72) gpT[threadIdx.x * N_GRAPHS + g] = acc[threadIdx.x];
}

// ---------------- MLP heads ----------------
struct HeadP {
  const float *w1, *b1, *g1, *be1, *w2, *b2, *g2, *be2, *w3, *b3;
};

__device__ inline float wred(float v) {
#pragma unroll
  for (int off = 32; off > 0; off >>= 1) v += __shfl_xor(v, off);
  return v;
}

__global__ __launch_bounds__(512) void head_l1_k(const float* __restrict__ gpT, HeadP hA,
                                                 HeadP hB, HeadP hC, float* __restrict__ h1T) {
  int head = blockIdx.x / 50, o = blockIdx.x % 50;
  HeadP hp = (head == 0) ? hA : ((head == 1) ? hB : hC);
  int r = threadIdx.x, lane = r & 63, wave = r >> 6;
  __shared__ float rs[8], rq[8], sc_sh, sh_sh;
  float acc = hp.b1[o];
  for (int k = 0; k < 72; k++) acc += gpT[k * N_GRAPHS + r] * hp.w1[k * 50 + o];
  float s = wred(acc), q = wred(acc * acc);
  if (lane == 0) { rs[wave] = s; rq[wave] = q; }
  __syncthreads();
  if (r == 0) {
    float ts = 0.f, tq = 0.f;
#pragma unroll
    for (int i = 0; i < 8; i++) { ts += rs[i]; tq += rq[i]; }
    float mu = ts / (float)N_GRAPHS;
    float var = tq / (float)N_GRAPHS - mu * mu;
    if (var < 0.f) var = 0.f;
    float sc = hp.g1[o] / sqrtf(var + 1e-5f);
    sc_sh = sc; sh_sh = hp.be1[o] - mu * sc;
  }
  __syncthreads();
  float v = acc * sc_sh + sh_sh;
  h1T[(head * 50 + o) * N_GRAPHS + r] = v > 0.f ? v : 0.f;
}

__global__ __launch_bounds__(512) void head_l2_k(const float* __restrict__ h1T, HeadP hA,
                                                 HeadP hB, HeadP hC, float* __restrict__ h2T) {
  int head = blockIdx.x / 25, o = blockIdx.x % 25;
  HeadP hp = (head == 0) ? hA : ((head == 1) ? hB : hC);
  int r = threadIdx.x, lane = r & 63, wave = r >> 6;
  __shared__ float rs[8], rq[8], sc_sh, sh_sh;
  float acc = hp.b2[o];
  const float* hb = h1T + head * 50 * N_GRAPHS;
  for (int k = 0; k < 50; k++) acc += hb[k * N_GRAPHS + r] * hp.w2[k * 25 + o];
  float s = wred(acc), q = wred(acc * acc);
  if (lane == 0) { rs[wave] = s; rq[wave] = q; }
  __syncthreads();
  if (r == 0) {
    float ts = 0.f, tq = 0.f;
#pragma unroll
    for (int i = 0; i < 8; i++) { ts += rs[i]; tq += rq[i]; }
    float mu = ts / (float)N_GRAPHS;
    float var = tq / (float)N_GRAPHS - mu * mu;
    if (var < 0.f) var = 0.f;
    float sc = hp.g2[o] / sqrtf(var + 1e-5f);
    sc_sh = sc; sh_sh = hp.be2[o] - mu * sc;
  }
  __syncthreads();
  float v = acc * sc_sh + sh_sh;
  h2T[(head * 25 + o) * N_GRAPHS + r] = v > 0.f ? v : 0.f;
}

__global__ __launch_bounds__(512) void head_l3_k(const float* __restrict__ h2T, HeadP hA,
                                                 HeadP hB, HeadP hC, float* __restrict__ out) {
  int head = blockIdx.x;
  HeadP hp = (head == 0) ? hA : ((head == 1) ? hB : hC);
  int r = threadIdx.x;
  int od = (head == 0) ? 3 : 7;
  float acc3[7];
#pragma unroll
  for (int o = 0; o < 7; o++) acc3[o] = (o < od) ? hp.b3[o] : 0.f;
  const float* hb = h2T + head * 25 * N_GRAPHS;
  for (int k = 0; k < 25; k++) {
    float hv = hb[k * N_GRAPHS + r];
#pragma unroll
    for (int o = 0; o < 7; o++)
      if (o < od) acc3[o] += hv * hp.w3[k * od + o];
  }
  float* og = out + r * 20;  // [512][2][10]
  if (head == 0) {
#pragma unroll
    for (int j = 0; j < 3; j++) {
      float v = tanhf(acc3[j]);
      og[7 + j] = v;
      og[17 + j] = v;
    }
  } else {
    const float unit[7] = {1.f, 1.f, 100.f, 0.01f, 1000.f, 0.f, 1e-5f};
    int base = (head == 1) ? 0 : 10;
#pragma unroll
    for (int j = 0; j < 7; j++) {
      float v = acc3[j];
      v = v > 0.f ? v : 0.f;
      og[base + j] = v + unit[j];
    }
  }
}

// ---------------- host launch ----------------
static inline char* alignp(char* p, size_t a) {
  return (char*)(((uintptr_t)p + (a - 1)) & ~(uintptr_t)(a - 1));
}

extern "C" void kernel_launch(void* const* d_in, const int* in_sizes, int n_in, void* d_out,
                              int out_size, void* d_ws, size_t ws_size, hipStream_t stream) {
  const float* x = (const float*)d_in[0];
  const float* edge_attr = (const float*)d_in[1];
  const int* srcp = (const int*)d_in[2];
  const int* dstp = srcp + N_EDGES;
  const int* batch = (const int*)d_in[3];

  const float *EWv[4], *EBv[4], *PRW[4], *PRB[4], *PW[4], *POB[4], *LWv[4], *LBv[4], *Gv[4],
      *BEv[4];
  EWv[0] = (const float*)d_in[4];  EBv[0] = (const float*)d_in[5];
  PRW[0] = (const float*)d_in[6];  PRB[0] = (const float*)d_in[7];
  PW[0] = (const float*)d_in[8];   POB[0] = (const float*)d_in[9];
  LWv[0] = (const float*)d_in[10]; LBv[0] = (const float*)d_in[11];
  Gv[0] = (const float*)d_in[12];  BEv[0] = (const float*)d_in[13];
  const float* cs_ew = (const float*)d_in[14];
  const float* cs_eb = (const float*)d_in[15];
  const float* cs_prw = (const float*)d_in[16];
  const float* cs_prb = (const float*)d_in[17];
  const float* cs_pow = (const float*)d_in[18];
  const float* cs_pob = (const float*)d_in[19];
  const float* cs_lw = (const float*)d_in[20];
  const float* cs_lb = (const float*)d_in[21];
  const float* cs_g = (const float*)d_in[22];
  const float* cs_be = (const float*)d_in[23];
  for (int i = 1; i < 4; i++) {
    int j = i - 1;
    EWv[i] = cs_ew + j * 3 * 72;        EBv[i] = cs_eb + j * 72;
    PRW[i] = cs_prw + j * 4 * 216 * 72; PRB[i] = cs_prb + j * 4 * 72;
    PW[i] = cs_pow + j * 4 * 936 * 18;  POB[i] = cs_pob + j * 4 * 18;
    LWv[i] = cs_lw + j * 72 * 72;       LBv[i] = cs_lb + j * 72;
    Gv[i] = cs_g + j * 72;              BEv[i] = cs_be + j * 72;
  }
  HeadP heads[3];
  for (int m = 0; m < 3; m++) {
    const float** pp = (const float**)&heads[m];
    for (int k = 0; k < 10; k++) pp[k] = (const float*)d_in[24 + m * 10 + k];
  }

  // workspace carve
  char* p = (char*)d_ws;
  int* deg_i = (int*)p;   p += N_NODES * 4;
  int* cursor = (int*)p;  p += N_NODES * 4;
  int* row_ptr = (int*)p; p += (N_NODES + 1) * 4;
  int* eids = (int*)p;    p += N_EDGES * 4;
  int* grp = (int*)p;     p += (N_GRAPHS + 1) * 4;
  p = alignp(p, 256);
  float* amp = (float*)p; p += N_NODES * 4;
  p = alignp(p, 256);
  float* R = (float*)p;   p += (size_t)N_NODES * 648 * 4;  // XdXs | y0 (cols 8F..8F+71)
  p = alignp(p, 256);
  float* y1 = (float*)p;  p += (size_t)N_NODES * 72 * 4;
  p = alignp(p, 256);
  unsigned short* aggh = (unsigned short*)p; p += (size_t)N_NODES * 1152 * 2;
  unsigned short* aggl = (unsigned short*)p; p += (size_t)N_NODES * 1152 * 2;
  p = alignp(p, 256);
  unsigned short* xh = (unsigned short*)p;   p += (size_t)N_NODES * 32 * 2;
  unsigned short* xl = (unsigned short*)p;   p += (size_t)N_NODES * 32 * 2;
  unsigned short* acth = (unsigned short*)p; p += (size_t)N_NODES * 96 * 2;
  unsigned short* actl = (unsigned short*)p; p += (size_t)N_NODES * 96 * 2;
  p = alignp(p, 256);
  unsigned short* BmTh = (unsigned short*)p; p += 648 * 96 * 2;
  unsigned short* BmTl = (unsigned short*)p; p += 648 * 96 * 2;
  unsigned short* WcTh = (unsigned short*)p; p += 4 * 64 * 288 * 2;
  unsigned short* WcTl = (unsigned short*)p; p += 4 * 64 * 288 * 2;
  p = alignp(p, 256);
  float* bfull = (float*)p; p += 648 * 4;
  float* Wec = (float*)p;   p += 3 * 288 * 4;
  float* bec = (float*)p;   p += 288 * 4;
  float* vsc = (float*)p;   p += 72 * 4;
  float* vsh = (float*)p;   p += 72 * 4;
  p = alignp(p, 256);
  double* bnsums = (double*)p; p += 144 * 8;
  p = alignp(p, 256);
  float* gpT = (float*)p;  p += 72 * N_GRAPHS * 4;
  float* h1T = (float*)p;  p += 3 * 50 * N_GRAPHS * 4;
  float* h2T = (float*)p;  p += 3 * 25 * N_GRAPHS * 4;
  (void)ws_size; (void)n_in; (void)in_sizes; (void)out_size;

  static const double hist[7] = {67167, 3157428, 5106064, 885236, 453935, 0, 11152};
  double num = 0, den = 0;
  for (int i = 0; i < 7; i++) { num += log((double)(i + 1)) * hist[i]; den += hist[i]; }
  float adl = (float)(num / den);

  // CSR + amp + graph boundaries + x split
  hipMemsetAsync(deg_i, 0, 2 * N_NODES * 4, stream);
  count_deg_k<<<(N_EDGES + 255) / 256, 256, 0, stream>>>(dstp, deg_i);
  scan_rowptr_k<<<1, 1024, 0, stream>>>(deg_i, row_ptr);
  fill_csr_k<<<(N_EDGES + 255) / 256, 256, 0, stream>>>(dstp, row_ptr, cursor, eids);
  amp_k<<<(N_NODES + 255) / 256, 256, 0, stream>>>(deg_i, amp, adl);
  gboundary_k<<<(N_NODES + 255) / 256, 256, 0, stream>>>(batch, grp);
  cvt_x_k<<<(N_NODES * 32 + 255) / 256, 256, 0, stream>>>(x, xh, xl);
  // zero k-pads of layer-0 agg split ([20000][4][64], real K=36 per tower)
  hipMemsetAsync(aggh, 0, (size_t)N_NODES * 256 * 2, stream);
  hipMemsetAsync(aggl, 0, (size_t)N_NODES * 256 * 2, stream);

  const int gM = (N_NODES + 127) / 128;  // 157
  for (int l = 0; l < 4; l++) {
    const int F = (l == 0) ? 9 : 72;
    const int C = 4 * F, Nfull = 8 * F + 72;
    const int KpA = (l == 0) ? 32 : 96;    // padded K for merged GEMM
    const int Kpz = (l == 0) ? 64 : 288;   // padded per-tower K for P-GEMM
    float* y0l = R + 8 * F;  // y0 columns at col offset 8F of merged output

    int nrep = Nfull * KpA + Nfull + 4 * 64 * Kpz + 3 * C + C;
    repack3_k<<<(nrep + 255) / 256, 256, 0, stream>>>(PRW[l], PW[l], EWv[l], EBv[l], PRB[l],
                                                      POB[l], BmTh, BmTl, bfull, WcTh, WcTl,
                                                      Wec, bec, F, KpA, Kpz);
    hipMemsetAsync(bnsums, 0, 144 * 8, stream);

    // merged GEMM (MFMA split-bf16): R[:, :Nfull] = act(prev) @ [Wd|Ws|W0] + [0|0|pob]
    {
      dim3 g(gM, (Nfull + 63) / 64, 1);
      mgemm_k<0><<<g, 256, 0, stream>>>((l == 0) ? xh : acth, (l == 0) ? xl : actl, BmTh, BmTl,
                                        R, bfull, N_NODES, Nfull, KpA, KpA, KpA, Nfull, 0, 0,
                                        nullptr, nullptr, 0);
    }

    // fused aggregation -> agg split hi/lo [N][4][Kpz]
    {
      long long tot = (long long)N_NODES * C;
      agg_fused_k<<<(int)((tot + 255) / 256), 256, 0, stream>>>(R, Nfull, edge_attr, srcp,
                                                                row_ptr, eids, Wec, bec, aggh,
                                                                aggl, F, Kpz);
    }

    // P-GEMM (MFMA split-bf16) with combine epilogue: y0 += combine(agg_t @ Wc_t, amp)
    {
      dim3 g(gM, 1, 4);
      mgemm_k<1><<<g, 256, 0, stream>>>(aggh, aggl, WcTh, WcTl, nullptr, nullptr, N_NODES, 64,
                                        Kpz, 4 * Kpz, Kpz, 0, Kpz, (long long)64 * Kpz, amp,
                                        y0l, Nfull);
    }

    // y1 = y0 @ lw + lb (fp32), with BN-stats epilogue
    {
      dim3 g(gM, 2, 1);
      sgemm2_k<1, 0, 2><<<g, 256, 0, stream>>>(y0l, LWv[l], y1, LBv[l], N_NODES, 72, 72, Nfull,
                                               72, 72, 72, 72, 0, 0, nullptr, nullptr, nullptr,
                                               nullptr, 0, bnsums);
    }

    bnfinal_k<<<1, 128, 0, stream>>>(bnsums, Gv[l], BEv[l], vsc, vsh);

    // pre-activate + split for next layer's merged GEMM
    if (l < 3)
      cvt_act_k<<<(N_NODES * 96 + 255) / 256, 256, 0, stream>>>(y1, vsc, vsh, acth, actl);
  }

  // pool with final BN+relu applied -> gpT [72][512]
  pool2_k<<<N_GRAPHS, 256, 0, stream>>>(y1, vsc, vsh, grp, gpT);

  head_l1_k<<<150, 512, 0, stream>>>(gpT, heads[0], heads[1], heads[2], h1T);
  head_l2_k<<<75, 512, 0, stream>>>(h1T, heads[0], heads[1], heads[2], h2T);
  head_l3_k<<<3, 512, 0, stream>>>(h2T, heads[0], heads[1], heads[2], (float*)d_out);
}